// Round 1
// baseline (6103.047 us; speedup 1.0000x reference)
//
#include <hip/hip_runtime.h>
#include <math.h>

#define BB 32
#define CC 128
#define HH 512
#define TT 8192
#define KMAX 512

#define NBIN 2048
#define CANDCAP 4096
#define HOTCAP 32768
#define HFLOOR 0.25f
#define BW (1.75f / 2048.0f)
#define DELTA 1e-4

// workspace layout (bytes)
#define OFF_HIST 0              // int[32][2048]          (zeroed)
#define OFF_SUMEXP 262144       // double[32]             (zeroed)
#define OFF_CANDCNT 262400      // int[32]                (zeroed)
#define OFF_HOTCNT 262528       // int[1]                 (zeroed)
#define ZERO_BYTES 262656
#define OFF_TAU 262656          // float[32]
#define OFF_SELCNT 262784       // int[32]
#define OFF_CELLMAX 263168      // float[2097152]
#define OFF_HOTLIST 8651776     // int[32768]
#define OFF_CANDVAL 8782848     // double[32*4096]
#define OFF_CANDIDX 9831424     // int[32*4096]
#define OFF_SELIDX 10355712     // int[32*512]
#define OFF_SELVAL 10421248     // float[32*512]

// ---------------- Pass A: fp32 GEMM (sal = sal_w @ x + sal_b) + stats ---------------
// grid (64, 4, 32), block 256. Tile 128h x 128t, microtile 8x8 per thread.
// Emits: cellmax (per-thread-footprint max), histogram of sal>=0.25, sum(exp(sal)).
__global__ __launch_bounds__(256) void pass_a(const float* __restrict__ x,
                                              const float* __restrict__ sw,
                                              const float* __restrict__ sb,
                                              float* __restrict__ cellmax,
                                              int* __restrict__ hist,
                                              double* __restrict__ sumexp) {
  __shared__ float Xs[2][8][128];
  __shared__ float Ws[2][8][128];
  int tid = threadIdx.x;
  int b = blockIdx.z, by = blockIdx.y, bx = blockIdx.x;
  int h0 = by * 128, t0 = bx * 128;
  const float* xb = x + (size_t)b * CC * TT;
  int th = tid >> 4, tt = tid & 15;
  float acc[8][8];
#pragma unroll
  for (int i = 0; i < 8; i++)
#pragma unroll
    for (int j = 0; j < 8; j++) acc[i][j] = 0.f;

  int cx = tid >> 5, tx = (tid & 31) << 2;   // X staging: row c, 4 t's
  int hw = tid >> 1, cw = (tid & 1) << 2;    // W staging: row h, 4 c's

  float4 rx = *(const float4*)(xb + (size_t)cx * TT + t0 + tx);
  float4 rw = *(const float4*)(sw + (size_t)(h0 + hw) * CC + cw);
  *(float4*)&Xs[0][cx][tx] = rx;
  Ws[0][cw + 0][hw] = rw.x;
  Ws[0][cw + 1][hw] = rw.y;
  Ws[0][cw + 2][hw] = rw.z;
  Ws[0][cw + 3][hw] = rw.w;
  __syncthreads();
  int p = 0;
  for (int kc = 0; kc < 16; kc++) {
    int c0n = (kc + 1) * 8;
    if (kc < 15) {
      rx = *(const float4*)(xb + (size_t)(c0n + cx) * TT + t0 + tx);
      rw = *(const float4*)(sw + (size_t)(h0 + hw) * CC + c0n + cw);
    }
#pragma unroll
    for (int kk = 0; kk < 8; kk++) {
      float wv[8], xv[8];
      *(float4*)&wv[0] = *(float4*)&Ws[p][kk][th * 8];
      *(float4*)&wv[4] = *(float4*)&Ws[p][kk][th * 8 + 4];
      *(float4*)&xv[0] = *(float4*)&Xs[p][kk][tt * 4];
      *(float4*)&xv[4] = *(float4*)&Xs[p][kk][64 + tt * 4];
#pragma unroll
      for (int i = 0; i < 8; i++)
#pragma unroll
        for (int j = 0; j < 8; j++) acc[i][j] = fmaf(wv[i], xv[j], acc[i][j]);
    }
    if (kc < 15) {
      int q = p ^ 1;
      *(float4*)&Xs[q][cx][tx] = rx;
      Ws[q][cw + 0][hw] = rw.x;
      Ws[q][cw + 1][hw] = rw.y;
      Ws[q][cw + 2][hw] = rw.z;
      Ws[q][cw + 3][hw] = rw.w;
      __syncthreads();
      p = q;
    }
  }
  // epilogue: bias + stats (sal never stored)
  float tmax = -1e30f;
  float se = 0.f;
#pragma unroll
  for (int i = 0; i < 8; i++) {
    float bias = sb[h0 + th * 8 + i];
#pragma unroll
    for (int j = 0; j < 8; j++) {
      float s = acc[i][j] + bias;
      tmax = fmaxf(tmax, s);
      se += __expf(s);
      if (s >= HFLOOR) {
        int bin = (int)((s - HFLOOR) * (1.0f / BW));
        if (bin > NBIN - 1) bin = NBIN - 1;
        atomicAdd(&hist[b * NBIN + bin], 1);
      }
    }
  }
  // per-thread footprint max; cell id == global pass_a thread id
  int cid = ((b * 4 + by) * 64 + bx) * 256 + tid;
  cellmax[cid] = tmax;
  double sed = (double)se;
#pragma unroll
  for (int m = 1; m < 64; m <<= 1) sed += __shfl_xor(sed, m);
  if ((tid & 63) == 0) atomicAdd(&sumexp[b], sed);
}

// ---------------- Pass B: per-batch threshold tau from histogram ----------------
__global__ void pass_b(const int* __restrict__ hist, float* __restrict__ tau,
                       const int* __restrict__ kptr) {
  __shared__ int hsh[NBIN];
  int b = blockIdx.x;
  for (int i = threadIdx.x; i < NBIN; i += blockDim.x) hsh[i] = hist[b * NBIN + i];
  __syncthreads();
  if (threadIdx.x == 0) {
    int k = kptr[0];
    if (k < 1) k = 1;
    if (k > KMAX) k = KMAX;
    long cum = 0;
    float tv = HFLOOR;
    for (int i = NBIN - 1; i >= 0; i--) {
      cum += hsh[i];
      if (cum >= k) { tv = HFLOOR + i * BW; break; }
    }
    tau[b] = tv;
  }
}

// ---------------- Pass C1: compact hot cells (cellmax >= tau - delta) ----------------
__global__ void pass_c1(const float* __restrict__ cellmax, const float* __restrict__ tau,
                        int* __restrict__ hotcnt, int* __restrict__ hotlist) {
  int i = blockIdx.x * blockDim.x + threadIdx.x;  // 2,097,152 total
  float v = cellmax[i];
  int b = i >> 16;
  if (v >= tau[b] - (float)DELTA) {
    int pos = atomicAdd(hotcnt, 1);
    if (pos < HOTCAP) hotlist[pos] = i;
  }
}

// ---------------- Pass C2: fp64 recompute of hot cells -> candidates ----------------
// block = 64 threads, one hot cell (the 8x8 footprint of one pass_a thread)
__global__ void pass_c2(const float* __restrict__ x, const float* __restrict__ sw,
                        const float* __restrict__ sb, const float* __restrict__ tau,
                        const int* __restrict__ hotcnt, const int* __restrict__ hotlist,
                        int* __restrict__ candcnt, double* __restrict__ candval,
                        int* __restrict__ candidx) {
  int j = blockIdx.x;
  int n = hotcnt[0];
  if (n > HOTCAP) n = HOTCAP;
  if (j >= n) return;
  int cid = hotlist[j];
  int b = cid >> 16, by = (cid >> 14) & 3, bx = (cid >> 8) & 63;
  int ta = cid & 255;
  int th = ta >> 4, tt = ta & 15;
  int i = threadIdx.x >> 3, jj = threadIdx.x & 7;
  int h = by * 128 + th * 8 + i;
  int t = bx * 128 + ((jj < 4) ? (tt * 4 + jj) : (64 + tt * 4 + jj - 4));
  const float* xb = x + (size_t)b * CC * TT;
  double acc = 0.0;
#pragma unroll 8
  for (int c = 0; c < CC; c++)
    acc += (double)xb[(size_t)c * TT + t] * (double)sw[h * CC + c];
  acc += (double)sb[h];
  float tm = tau[b] - (float)DELTA;
  if (acc >= (double)tm) {
    int pos = atomicAdd(&candcnt[b], 1);
    if (pos < CANDCAP) {
      candval[b * CANDCAP + pos] = acc;
      candidx[b * CANDCAP + pos] = h * TT + t;
    }
  }
}

// ---------------- Pass D: exact top-k among candidates (rank = unique slot) ----------
__global__ void pass_d(const int* __restrict__ candcnt, const double* __restrict__ candval,
                       const int* __restrict__ candidx, const double* __restrict__ sumexp,
                       const int* __restrict__ kptr, int* __restrict__ selidx,
                       float* __restrict__ selval, int* __restrict__ selcnt) {
  __shared__ double sv[CANDCAP];
  __shared__ int si[CANDCAP];
  int b = blockIdx.x;
  int n = candcnt[b];
  if (n > CANDCAP) n = CANDCAP;
  int k = kptr[0];
  if (k < 0) k = 0;
  if (k > KMAX) k = KMAX;
  for (int i = threadIdx.x; i < n; i += blockDim.x) {
    sv[i] = candval[b * CANDCAP + i];
    si[i] = candidx[b * CANDCAP + i];
  }
  __syncthreads();
  double S = sumexp[b];
  for (int i = threadIdx.x; i < n; i += blockDim.x) {
    double vi = sv[i];
    int ii = si[i];
    int rank = 0;
    for (int q = 0; q < n; q++) {
      double vq = sv[q];
      rank += (vq > vi) || (vq == vi && si[q] < ii);
    }
    if (rank < k) {
      selidx[b * KMAX + rank] = ii;
      selval[b * KMAX + rank] = (float)(exp(vi) / S);
    }
  }
  if (threadIdx.x == 0) selcnt[b] = n < k ? n : k;
}

// ---------------- Pass E1: out = down_b broadcast ----------------
__global__ void pass_e1(const float* __restrict__ db, float* __restrict__ out) {
  int row = blockIdx.x;  // b*C + c
  int c = row & (CC - 1);
  float v = db[c];
  float4 v4 = make_float4(v, v, v, v);
  float4* o = (float4*)(out + (size_t)row * TT);
#pragma unroll
  for (int q = 0; q < 8; q++) o[q * 256 + threadIdx.x] = v4;
}

// ---------------- Pass E2: scatter — sig dot + rank-1 update per selected ----------
__global__ void pass_e2(const float* __restrict__ x, const float* __restrict__ uw,
                        const float* __restrict__ ub, const float* __restrict__ dw,
                        const int* __restrict__ selidx, const float* __restrict__ selval,
                        const int* __restrict__ selcnt, float* __restrict__ out) {
  int b = blockIdx.y, j = blockIdx.x;
  if (j >= selcnt[b]) return;
  int idx = selidx[b * KMAX + j];
  float val = selval[b * KMAX + j];
  int h = idx >> 13, t = idx & (TT - 1);
  int c = threadIdx.x;  // 64 threads: lanes handle c and c+64
  const float* xb = x + (size_t)b * CC * TT;
  float p = xb[(size_t)c * TT + t] * uw[h * CC + c] +
            xb[(size_t)(c + 64) * TT + t] * uw[h * CC + c + 64];
#pragma unroll
  for (int m = 1; m < 64; m <<= 1) p += __shfl_xor(p, m);
  float sig = p + ub[h];
  float g = sig * val;
  atomicAdd(&out[((size_t)b * CC + c) * TT + t], g * dw[c * HH + h]);
  atomicAdd(&out[((size_t)b * CC + c + 64) * TT + t], g * dw[(c + 64) * HH + h]);
}

extern "C" void kernel_launch(void* const* d_in, const int* in_sizes, int n_in,
                              void* d_out, int out_size, void* d_ws, size_t ws_size,
                              hipStream_t stream) {
  const float* x = (const float*)d_in[0];
  const float* uw = (const float*)d_in[1];
  const float* ub = (const float*)d_in[2];
  const float* sw = (const float*)d_in[3];
  const float* sb = (const float*)d_in[4];
  const float* dw = (const float*)d_in[5];
  const float* db = (const float*)d_in[6];
  const int* kptr = (const int*)d_in[7];
  float* out = (float*)d_out;
  char* ws = (char*)d_ws;

  int* hist = (int*)(ws + OFF_HIST);
  double* sumexp = (double*)(ws + OFF_SUMEXP);
  int* candcnt = (int*)(ws + OFF_CANDCNT);
  int* hotcnt = (int*)(ws + OFF_HOTCNT);
  float* tau = (float*)(ws + OFF_TAU);
  int* selcnt = (int*)(ws + OFF_SELCNT);
  float* cellmax = (float*)(ws + OFF_CELLMAX);
  int* hotlist = (int*)(ws + OFF_HOTLIST);
  double* candval = (double*)(ws + OFF_CANDVAL);
  int* candidx = (int*)(ws + OFF_CANDIDX);
  int* selidx = (int*)(ws + OFF_SELIDX);
  float* selval = (float*)(ws + OFF_SELVAL);

  (void)hipMemsetAsync(d_ws, 0, ZERO_BYTES, stream);
  pass_a<<<dim3(64, 4, 32), 256, 0, stream>>>(x, sw, sb, cellmax, hist, sumexp);
  pass_b<<<32, 256, 0, stream>>>(hist, tau, kptr);
  pass_c1<<<8192, 256, 0, stream>>>(cellmax, tau, hotcnt, hotlist);
  pass_c2<<<HOTCAP, 64, 0, stream>>>(x, sw, sb, tau, hotcnt, hotlist, candcnt, candval,
                                     candidx);
  pass_d<<<32, 256, 0, stream>>>(candcnt, candval, candidx, sumexp, kptr, selidx, selval,
                                 selcnt);
  pass_e1<<<BB * CC, 256, 0, stream>>>(db, out);
  pass_e2<<<dim3(KMAX, BB), 64, 0, stream>>>(x, uw, ub, dw, selidx, selval, selcnt, out);
}

// Round 2
// 1303.089 us; speedup vs baseline: 4.6835x; 4.6835x over previous
//
#include <hip/hip_runtime.h>
#include <math.h>

#define BB 32
#define CC 128
#define HH 512
#define TT 8192
#define KMAX 512

#define NBIN 2048
#define CANDCAP 4096
#define HOTCAP 32768
// Histogram floor: sal std ~= 0.226; tau ~= 0.83 (K-th of 4.19M). Floor 0.6 keeps
// ~17k entries/batch above floor (33x margin over K=512) while cutting global
// atomics from 18M (floor 0.25 -> 519MB HBM RMW traffic, R1 bottleneck) to ~0.5M.
#define HFLOOR 0.6f
#define BW (0.875f / 2048.0f)
#define DELTA 1e-4

// workspace layout (bytes)
#define OFF_HIST 0              // int[32][2048]          (zeroed)
#define OFF_SUMEXP 262144       // double[32]             (zeroed)
#define OFF_CANDCNT 262400      // int[32]                (zeroed)
#define OFF_HOTCNT 262528       // int[1]                 (zeroed)
#define ZERO_BYTES 262656
#define OFF_TAU 262656          // float[32]
#define OFF_SELCNT 262784       // int[32]
#define OFF_CELLMAX 263168      // float[2097152]
#define OFF_HOTLIST 8651776     // int[32768]
#define OFF_CANDVAL 8782848     // double[32*4096]
#define OFF_CANDIDX 9831424     // int[32*4096]
#define OFF_SELIDX 10355712     // int[32*512]
#define OFF_SELVAL 10421248     // float[32*512]

// ---------------- Pass A: fp32 GEMM (sal = sal_w @ x + sal_b) + stats ---------------
// grid (64, 4, 32), block 256. Tile 128h x 128t, microtile 8x8 per thread.
// Emits: cellmax (per-thread-footprint max), histogram of sal>=HFLOOR, sum(exp(sal)).
__global__ __launch_bounds__(256) void pass_a(const float* __restrict__ x,
                                              const float* __restrict__ sw,
                                              const float* __restrict__ sb,
                                              float* __restrict__ cellmax,
                                              int* __restrict__ hist,
                                              double* __restrict__ sumexp) {
  __shared__ float Xs[2][8][128];
  __shared__ float Ws[2][8][128];
  int tid = threadIdx.x;
  int b = blockIdx.z, by = blockIdx.y, bx = blockIdx.x;
  int h0 = by * 128, t0 = bx * 128;
  const float* xb = x + (size_t)b * CC * TT;
  int th = tid >> 4, tt = tid & 15;
  float acc[8][8];
#pragma unroll
  for (int i = 0; i < 8; i++)
#pragma unroll
    for (int j = 0; j < 8; j++) acc[i][j] = 0.f;

  int cx = tid >> 5, tx = (tid & 31) << 2;   // X staging: row c, 4 t's
  int hw = tid >> 1, cw = (tid & 1) << 2;    // W staging: row h, 4 c's

  float4 rx = *(const float4*)(xb + (size_t)cx * TT + t0 + tx);
  float4 rw = *(const float4*)(sw + (size_t)(h0 + hw) * CC + cw);
  *(float4*)&Xs[0][cx][tx] = rx;
  Ws[0][cw + 0][hw] = rw.x;
  Ws[0][cw + 1][hw] = rw.y;
  Ws[0][cw + 2][hw] = rw.z;
  Ws[0][cw + 3][hw] = rw.w;
  __syncthreads();
  int p = 0;
  for (int kc = 0; kc < 16; kc++) {
    int c0n = (kc + 1) * 8;
    if (kc < 15) {
      rx = *(const float4*)(xb + (size_t)(c0n + cx) * TT + t0 + tx);
      rw = *(const float4*)(sw + (size_t)(h0 + hw) * CC + c0n + cw);
    }
#pragma unroll
    for (int kk = 0; kk < 8; kk++) {
      float wv[8], xv[8];
      *(float4*)&wv[0] = *(float4*)&Ws[p][kk][th * 8];
      *(float4*)&wv[4] = *(float4*)&Ws[p][kk][th * 8 + 4];
      *(float4*)&xv[0] = *(float4*)&Xs[p][kk][tt * 4];
      *(float4*)&xv[4] = *(float4*)&Xs[p][kk][64 + tt * 4];
#pragma unroll
      for (int i = 0; i < 8; i++)
#pragma unroll
        for (int j = 0; j < 8; j++) acc[i][j] = fmaf(wv[i], xv[j], acc[i][j]);
    }
    if (kc < 15) {
      int q = p ^ 1;
      *(float4*)&Xs[q][cx][tx] = rx;
      Ws[q][cw + 0][hw] = rw.x;
      Ws[q][cw + 1][hw] = rw.y;
      Ws[q][cw + 2][hw] = rw.z;
      Ws[q][cw + 3][hw] = rw.w;
      __syncthreads();
      p = q;
    }
  }
  // epilogue: bias + stats (sal never stored)
  float tmax = -1e30f;
  float se = 0.f;
#pragma unroll
  for (int i = 0; i < 8; i++) {
    float bias = sb[h0 + th * 8 + i];
#pragma unroll
    for (int j = 0; j < 8; j++) {
      float s = acc[i][j] + bias;
      tmax = fmaxf(tmax, s);
      se += __expf(s);
      if (s >= HFLOOR) {
        int bin = (int)((s - HFLOOR) * (1.0f / BW));
        if (bin > NBIN - 1) bin = NBIN - 1;
        atomicAdd(&hist[b * NBIN + bin], 1);
      }
    }
  }
  // per-thread footprint max; cell id == global pass_a thread id
  int cid = ((b * 4 + by) * 64 + bx) * 256 + tid;
  cellmax[cid] = tmax;
  double sed = (double)se;
#pragma unroll
  for (int m = 1; m < 64; m <<= 1) sed += __shfl_xor(sed, m);
  if ((tid & 63) == 0) atomicAdd(&sumexp[b], sed);
}

// ---------------- Pass B: per-batch threshold tau from histogram ----------------
__global__ void pass_b(const int* __restrict__ hist, float* __restrict__ tau,
                       const int* __restrict__ kptr) {
  __shared__ int hsh[NBIN];
  int b = blockIdx.x;
  for (int i = threadIdx.x; i < NBIN; i += blockDim.x) hsh[i] = hist[b * NBIN + i];
  __syncthreads();
  if (threadIdx.x == 0) {
    int k = kptr[0];
    if (k < 1) k = 1;
    if (k > KMAX) k = KMAX;
    long cum = 0;
    float tv = HFLOOR;
    for (int i = NBIN - 1; i >= 0; i--) {
      cum += hsh[i];
      if (cum >= k) { tv = HFLOOR + i * BW; break; }
    }
    tau[b] = tv;
  }
}

// ---------------- Pass C1: compact hot cells (cellmax >= tau - delta) ----------------
__global__ void pass_c1(const float* __restrict__ cellmax, const float* __restrict__ tau,
                        int* __restrict__ hotcnt, int* __restrict__ hotlist) {
  int i = blockIdx.x * blockDim.x + threadIdx.x;  // 2,097,152 total
  float v = cellmax[i];
  int b = i >> 16;
  if (v >= tau[b] - (float)DELTA) {
    int pos = atomicAdd(hotcnt, 1);
    if (pos < HOTCAP) hotlist[pos] = i;
  }
}

// ---------------- Pass C2: fp64 recompute of hot cells -> candidates ----------------
// block = 64 threads, one hot cell (the 8x8 footprint of one pass_a thread)
__global__ void pass_c2(const float* __restrict__ x, const float* __restrict__ sw,
                        const float* __restrict__ sb, const float* __restrict__ tau,
                        const int* __restrict__ hotcnt, const int* __restrict__ hotlist,
                        int* __restrict__ candcnt, double* __restrict__ candval,
                        int* __restrict__ candidx) {
  int j = blockIdx.x;
  int n = hotcnt[0];
  if (n > HOTCAP) n = HOTCAP;
  if (j >= n) return;
  int cid = hotlist[j];
  int b = cid >> 16, by = (cid >> 14) & 3, bx = (cid >> 8) & 63;
  int ta = cid & 255;
  int th = ta >> 4, tt = ta & 15;
  int i = threadIdx.x >> 3, jj = threadIdx.x & 7;
  int h = by * 128 + th * 8 + i;
  int t = bx * 128 + ((jj < 4) ? (tt * 4 + jj) : (64 + tt * 4 + jj - 4));
  const float* xb = x + (size_t)b * CC * TT;
  double acc = 0.0;
#pragma unroll 8
  for (int c = 0; c < CC; c++)
    acc += (double)xb[(size_t)c * TT + t] * (double)sw[h * CC + c];
  acc += (double)sb[h];
  float tm = tau[b] - (float)DELTA;
  if (acc >= (double)tm) {
    int pos = atomicAdd(&candcnt[b], 1);
    if (pos < CANDCAP) {
      candval[b * CANDCAP + pos] = acc;
      candidx[b * CANDCAP + pos] = h * TT + t;
    }
  }
}

// ---------------- Pass D: exact top-k among candidates (rank = unique slot) ----------
__global__ void pass_d(const int* __restrict__ candcnt, const double* __restrict__ candval,
                       const int* __restrict__ candidx, const double* __restrict__ sumexp,
                       const int* __restrict__ kptr, int* __restrict__ selidx,
                       float* __restrict__ selval, int* __restrict__ selcnt) {
  __shared__ double sv[CANDCAP];
  __shared__ int si[CANDCAP];
  int b = blockIdx.x;
  int n = candcnt[b];
  if (n > CANDCAP) n = CANDCAP;
  int k = kptr[0];
  if (k < 0) k = 0;
  if (k > KMAX) k = KMAX;
  for (int i = threadIdx.x; i < n; i += blockDim.x) {
    sv[i] = candval[b * CANDCAP + i];
    si[i] = candidx[b * CANDCAP + i];
  }
  __syncthreads();
  double S = sumexp[b];
  for (int i = threadIdx.x; i < n; i += blockDim.x) {
    double vi = sv[i];
    int ii = si[i];
    int rank = 0;
    for (int q = 0; q < n; q++) {
      double vq = sv[q];
      rank += (vq > vi) || (vq == vi && si[q] < ii);
    }
    if (rank < k) {
      selidx[b * KMAX + rank] = ii;
      selval[b * KMAX + rank] = (float)(exp(vi) / S);
    }
  }
  if (threadIdx.x == 0) selcnt[b] = n < k ? n : k;
}

// ---------------- Pass E1: out = down_b broadcast ----------------
__global__ void pass_e1(const float* __restrict__ db, float* __restrict__ out) {
  int row = blockIdx.x;  // b*C + c
  int c = row & (CC - 1);
  float v = db[c];
  float4 v4 = make_float4(v, v, v, v);
  float4* o = (float4*)(out + (size_t)row * TT);
#pragma unroll
  for (int q = 0; q < 8; q++) o[q * 256 + threadIdx.x] = v4;
}

// ---------------- Pass E2: scatter — sig dot + rank-1 update per selected ----------
__global__ void pass_e2(const float* __restrict__ x, const float* __restrict__ uw,
                        const float* __restrict__ ub, const float* __restrict__ dw,
                        const int* __restrict__ selidx, const float* __restrict__ selval,
                        const int* __restrict__ selcnt, float* __restrict__ out) {
  int b = blockIdx.y, j = blockIdx.x;
  if (j >= selcnt[b]) return;
  int idx = selidx[b * KMAX + j];
  float val = selval[b * KMAX + j];
  int h = idx >> 13, t = idx & (TT - 1);
  int c = threadIdx.x;  // 64 threads: lanes handle c and c+64
  const float* xb = x + (size_t)b * CC * TT;
  float p = xb[(size_t)c * TT + t] * uw[h * CC + c] +
            xb[(size_t)(c + 64) * TT + t] * uw[h * CC + c + 64];
#pragma unroll
  for (int m = 1; m < 64; m <<= 1) p += __shfl_xor(p, m);
  float sig = p + ub[h];
  float g = sig * val;
  atomicAdd(&out[((size_t)b * CC + c) * TT + t], g * dw[c * HH + h]);
  atomicAdd(&out[((size_t)b * CC + c + 64) * TT + t], g * dw[(c + 64) * HH + h]);
}

extern "C" void kernel_launch(void* const* d_in, const int* in_sizes, int n_in,
                              void* d_out, int out_size, void* d_ws, size_t ws_size,
                              hipStream_t stream) {
  const float* x = (const float*)d_in[0];
  const float* uw = (const float*)d_in[1];
  const float* ub = (const float*)d_in[2];
  const float* sw = (const float*)d_in[3];
  const float* sb = (const float*)d_in[4];
  const float* dw = (const float*)d_in[5];
  const float* db = (const float*)d_in[6];
  const int* kptr = (const int*)d_in[7];
  float* out = (float*)d_out;
  char* ws = (char*)d_ws;

  int* hist = (int*)(ws + OFF_HIST);
  double* sumexp = (double*)(ws + OFF_SUMEXP);
  int* candcnt = (int*)(ws + OFF_CANDCNT);
  int* hotcnt = (int*)(ws + OFF_HOTCNT);
  float* tau = (float*)(ws + OFF_TAU);
  int* selcnt = (int*)(ws + OFF_SELCNT);
  float* cellmax = (float*)(ws + OFF_CELLMAX);
  int* hotlist = (int*)(ws + OFF_HOTLIST);
  double* candval = (double*)(ws + OFF_CANDVAL);
  int* candidx = (int*)(ws + OFF_CANDIDX);
  int* selidx = (int*)(ws + OFF_SELIDX);
  float* selval = (float*)(ws + OFF_SELVAL);

  (void)hipMemsetAsync(d_ws, 0, ZERO_BYTES, stream);
  pass_a<<<dim3(64, 4, 32), 256, 0, stream>>>(x, sw, sb, cellmax, hist, sumexp);
  pass_b<<<32, 256, 0, stream>>>(hist, tau, kptr);
  pass_c1<<<8192, 256, 0, stream>>>(cellmax, tau, hotcnt, hotlist);
  pass_c2<<<HOTCAP, 64, 0, stream>>>(x, sw, sb, tau, hotcnt, hotlist, candcnt, candval,
                                     candidx);
  pass_d<<<32, 256, 0, stream>>>(candcnt, candval, candidx, sumexp, kptr, selidx, selval,
                                 selcnt);
  pass_e1<<<BB * CC, 256, 0, stream>>>(db, out);
  pass_e2<<<dim3(KMAX, BB), 64, 0, stream>>>(x, uw, ub, dw, selidx, selval, selcnt, out);
}

// Round 3
// 1233.858 us; speedup vs baseline: 4.9463x; 1.0561x over previous
//
#include <hip/hip_runtime.h>
#include <hip/hip_bf16.h>
#include <math.h>

#define BB 32
#define CC 128
#define HH 512
#define TT 8192
#define KMAX 512

#define NBIN 2048
#define CANDCAP 4096
#define HOTCAP 32768
// tau ~= 0.83; floor 0.6 keeps ~17k hist entries/batch (33x over K) -> ~0.5M atomics.
#define HFLOOR 0.6f
#define BW (0.875f / 2048.0f)
#define INVBW (2048.0f / 0.875f)
// bf16-MFMA sal noise: sigma ~2.6e-4, worst-case ~3e-3. Margins:
#define DELTA_C2 6e-3f   // candidate slack vs tau (fp64-verified values)
#define DELTA_C1 1.2e-2f // hot-cell slack: candidate slack + bf16 cellmax noise

// workspace layout (bytes)
#define OFF_HIST 0              // int[32][2048]          (zeroed)
#define OFF_SUMEXP 262144       // double[32]             (zeroed)
#define OFF_CANDCNT 262400      // int[32]                (zeroed)
#define OFF_HOTCNT 262528       // int[1]                 (zeroed)
#define ZERO_BYTES 262656
#define OFF_TAU 262656          // float[32]
#define OFF_SELCNT 262784       // int[32]
#define OFF_CELLMAX 263168      // float[2097152]
#define OFF_HOTLIST 8651776     // int[32768]
#define OFF_CANDVAL 8782848     // double[32*4096]
#define OFF_CANDIDX 9831424     // int[32*4096]
#define OFF_SELIDX 10355712     // int[32*512]
#define OFF_SELVAL 10421248     // float[32*512]

typedef __attribute__((ext_vector_type(8))) short short8;
typedef __attribute__((ext_vector_type(16))) float f32x16;

// ---------------- Pass A: bf16 MFMA GEMM (sal = sal_w @ x + sal_b) + stats ----------
// grid (64, 4, 32), block 256 (4 waves). Tile 128h x 128t, K=C=128 staged once.
// Wave w computes h-rows [w*32, w*32+32) x all 128 t via 4x mfma_32x32x16_bf16 tiles.
// LDS: bf16, XOR-swizzled in 8-short blocks (conflict-free ds_read_b128):
//   addr_short(row, c) = row*128 + (((c>>3) ^ (row&15))<<3) + (c&7)
// Ws rows = h (k=c contiguous); Xs rows = t (transposed at staging; k=c contiguous).
__global__ __launch_bounds__(256) void pass_a(const float* __restrict__ x,
                                              const float* __restrict__ sw,
                                              const float* __restrict__ sb,
                                              float* __restrict__ cellmax,
                                              int* __restrict__ hist,
                                              double* __restrict__ sumexp) {
  __shared__ short Ws[128 * 128];
  __shared__ short Xs[128 * 128];
  __shared__ float sbs[128];
  int tid = threadIdx.x;
  int b = blockIdx.z, by = blockIdx.y, bx = blockIdx.x;
  int h0 = by * 128, t0g = bx * 128;
  const float* xb = x + (size_t)b * CC * TT;

  // ---- stage X (fp32 -> bf16, transpose to [t][c]) ----
  {
    int cq = tid >> 5, tq = tid & 31;
    int t0 = tq * 4;
#pragma unroll
    for (int p = 0; p < 4; p++) {
      int c0 = p * 32 + cq * 4;
      float r0[4], r1[4], r2[4], r3[4];
      *(float4*)r0 = *(const float4*)(xb + (size_t)(c0 + 0) * TT + t0g + t0);
      *(float4*)r1 = *(const float4*)(xb + (size_t)(c0 + 1) * TT + t0g + t0);
      *(float4*)r2 = *(const float4*)(xb + (size_t)(c0 + 2) * TT + t0g + t0);
      *(float4*)r3 = *(const float4*)(xb + (size_t)(c0 + 3) * TT + t0g + t0);
#pragma unroll
      for (int j = 0; j < 4; j++) {
        int t = t0 + j;
        int addr = t * 128 + ((((c0 >> 3) ^ (t & 15)) << 3) | (c0 & 7));
        union { __hip_bfloat162 h; unsigned int u; } a0, a1;
        a0.h = __float22bfloat162_rn(make_float2(r0[j], r1[j]));
        a1.h = __float22bfloat162_rn(make_float2(r2[j], r3[j]));
        *(uint2*)&Xs[addr] = make_uint2(a0.u, a1.u);
      }
    }
  }
  // ---- stage W (fp32 -> bf16, [h][c]) ----
  {
    int hh = tid >> 1, c4 = (tid & 1) * 4;
#pragma unroll
    for (int k = 0; k < 16; k++) {
      int c0 = k * 8 + c4;
      float r[4];
      *(float4*)r = *(const float4*)(sw + (size_t)(h0 + hh) * CC + c0);
      int addr = hh * 128 + ((((c0 >> 3) ^ (hh & 15)) << 3) | (c0 & 7));
      union { __hip_bfloat162 h; unsigned int u; } a0, a1;
      a0.h = __float22bfloat162_rn(make_float2(r[0], r[1]));
      a1.h = __float22bfloat162_rn(make_float2(r[2], r[3]));
      *(uint2*)&Ws[addr] = make_uint2(a0.u, a1.u);
    }
  }
  if (tid < 128) sbs[tid] = sb[h0 + tid];
  __syncthreads();

  // ---- MFMA main: 8 K-chunks x (1 A-frag + 4 B-frags) ----
  int w = tid >> 6, lane = tid & 63, m = lane & 31, u = lane >> 5;
  f32x16 acc0, acc1, acc2, acc3;
#pragma unroll
  for (int r = 0; r < 16; r++) { acc0[r] = 0.f; acc1[r] = 0.f; acc2[r] = 0.f; acc3[r] = 0.f; }
  const short* wrow = &Ws[(w * 32 + m) * 128];
  const short* xrow = &Xs[m * 128];
#pragma unroll
  for (int kc = 0; kc < 8; kc++) {
    int pc = ((((kc << 1) | u) ^ (m & 15)) << 3);
    short8 af = *(const short8*)(wrow + pc);
    short8 b0 = *(const short8*)(xrow + 0 * 32 * 128 + pc);
    short8 b1 = *(const short8*)(xrow + 1 * 32 * 128 + pc);
    short8 b2 = *(const short8*)(xrow + 2 * 32 * 128 + pc);
    short8 b3 = *(const short8*)(xrow + 3 * 32 * 128 + pc);
    acc0 = __builtin_amdgcn_mfma_f32_32x32x16_bf16(af, b0, acc0, 0, 0, 0);
    acc1 = __builtin_amdgcn_mfma_f32_32x32x16_bf16(af, b1, acc1, 0, 0, 0);
    acc2 = __builtin_amdgcn_mfma_f32_32x32x16_bf16(af, b2, acc2, 0, 0, 0);
    acc3 = __builtin_amdgcn_mfma_f32_32x32x16_bf16(af, b3, acc3, 0, 0, 0);
  }

  // ---- epilogue: bias + max + exp + hist. C/D: col(t)=lane&31, row(h)=8g+q+4u ----
  float tmax = -1e30f;
  float se = 0.f;
#define EPI(ACC)                                                              \
  {                                                                           \
    _Pragma("unroll") for (int g = 0; g < 4; g++) {                           \
      float bias4[4];                                                         \
      *(float4*)bias4 = *(float4*)&sbs[w * 32 + g * 8 + u * 4];               \
      _Pragma("unroll") for (int q = 0; q < 4; q++) {                         \
        float s = ACC[g * 4 + q] + bias4[q];                                  \
        tmax = fmaxf(tmax, s);                                                \
        se += __expf(s);                                                      \
        if (s >= HFLOOR) {                                                    \
          int bin = (int)((s - HFLOOR) * INVBW);                              \
          if (bin > NBIN - 1) bin = NBIN - 1;                                 \
          atomicAdd(&hist[b * NBIN + bin], 1);                                \
        }                                                                     \
      }                                                                       \
    }                                                                         \
  }
  EPI(acc0) EPI(acc1) EPI(acc2) EPI(acc3)
#undef EPI

  // cell = this thread's 64 accumulator elements; cid = global pass_a thread id
  int cid = ((b * 4 + by) * 64 + bx) * 256 + tid;
  cellmax[cid] = tmax;
  double sed = (double)se;
#pragma unroll
  for (int mm = 1; mm < 64; mm <<= 1) sed += __shfl_xor(sed, mm);
  if ((tid & 63) == 0) atomicAdd(&sumexp[b], sed);
}

// ---------------- Pass B: per-batch threshold tau from histogram ----------------
__global__ void pass_b(const int* __restrict__ hist, float* __restrict__ tau,
                       const int* __restrict__ kptr) {
  __shared__ int hsh[NBIN];
  int b = blockIdx.x;
  for (int i = threadIdx.x; i < NBIN; i += blockDim.x) hsh[i] = hist[b * NBIN + i];
  __syncthreads();
  if (threadIdx.x == 0) {
    int k = kptr[0];
    if (k < 1) k = 1;
    if (k > KMAX) k = KMAX;
    long cum = 0;
    float tv = HFLOOR;
    for (int i = NBIN - 1; i >= 0; i--) {
      cum += hsh[i];
      if (cum >= k) { tv = HFLOOR + i * BW; break; }
    }
    tau[b] = tv;
  }
}

// ---------------- Pass C1: compact hot cells (cellmax >= tau - DELTA_C1) ------------
__global__ void pass_c1(const float* __restrict__ cellmax, const float* __restrict__ tau,
                        int* __restrict__ hotcnt, int* __restrict__ hotlist) {
  int i = blockIdx.x * blockDim.x + threadIdx.x;  // 2,097,152 total
  float v = cellmax[i];
  int b = i >> 16;
  if (v >= tau[b] - DELTA_C1) {
    int pos = atomicAdd(hotcnt, 1);
    if (pos < HOTCAP) hotlist[pos] = i;
  }
}

// ---------------- Pass C2: fp64 recompute of hot cells -> candidates ----------------
// block = 64 threads, one hot cell = one pass_a thread's 64 MFMA accumulator elements.
// Decode: cid = block*256 + tid; element e: nt=e>>4, r=e&15 ->
//   h = by*128 + w*32 + 8*(r>>2) + (r&3) + 4*u ;  t = bx*128 + nt*32 + m
__global__ void pass_c2(const float* __restrict__ x, const float* __restrict__ sw,
                        const float* __restrict__ sb, const float* __restrict__ tau,
                        const int* __restrict__ hotcnt, const int* __restrict__ hotlist,
                        int* __restrict__ candcnt, double* __restrict__ candval,
                        int* __restrict__ candidx) {
  int j = blockIdx.x;
  int n = hotcnt[0];
  if (n > HOTCAP) n = HOTCAP;
  if (j >= n) return;
  int cid = hotlist[j];
  int b = cid >> 16, by = (cid >> 14) & 3, bx = (cid >> 8) & 63;
  int ta = cid & 255;
  int w = ta >> 6, lane = ta & 63, m = lane & 31, u = lane >> 5;
  int e = threadIdx.x;
  int nt = e >> 4, r = e & 15;
  int h = by * 128 + w * 32 + (r >> 2) * 8 + (r & 3) + 4 * u;
  int t = bx * 128 + nt * 32 + m;
  const float* xb = x + (size_t)b * CC * TT;
  double acc = 0.0;
#pragma unroll 8
  for (int c = 0; c < CC; c++)
    acc += (double)xb[(size_t)c * TT + t] * (double)sw[h * CC + c];
  acc += (double)sb[h];
  float tm = tau[b] - DELTA_C2;
  if (acc >= (double)tm) {
    int pos = atomicAdd(&candcnt[b], 1);
    if (pos < CANDCAP) {
      candval[b * CANDCAP + pos] = acc;
      candidx[b * CANDCAP + pos] = h * TT + t;
    }
  }
}

// ---------------- Pass D: exact top-k among candidates (rank = unique slot) ----------
__global__ void pass_d(const int* __restrict__ candcnt, const double* __restrict__ candval,
                       const int* __restrict__ candidx, const double* __restrict__ sumexp,
                       const int* __restrict__ kptr, int* __restrict__ selidx,
                       float* __restrict__ selval, int* __restrict__ selcnt) {
  __shared__ double sv[CANDCAP];
  __shared__ int si[CANDCAP];
  int b = blockIdx.x;
  int n = candcnt[b];
  if (n > CANDCAP) n = CANDCAP;
  int k = kptr[0];
  if (k < 0) k = 0;
  if (k > KMAX) k = KMAX;
  for (int i = threadIdx.x; i < n; i += blockDim.x) {
    sv[i] = candval[b * CANDCAP + i];
    si[i] = candidx[b * CANDCAP + i];
  }
  __syncthreads();
  double S = sumexp[b];
  for (int i = threadIdx.x; i < n; i += blockDim.x) {
    double vi = sv[i];
    int ii = si[i];
    int rank = 0;
    for (int q = 0; q < n; q++) {
      double vq = sv[q];
      rank += (vq > vi) || (vq == vi && si[q] < ii);
    }
    if (rank < k) {
      selidx[b * KMAX + rank] = ii;
      selval[b * KMAX + rank] = (float)(exp(vi) / S);
    }
  }
  if (threadIdx.x == 0) selcnt[b] = n < k ? n : k;
}

// ---------------- Pass E1: out = down_b broadcast ----------------
__global__ void pass_e1(const float* __restrict__ db, float* __restrict__ out) {
  int row = blockIdx.x;  // b*C + c
  int c = row & (CC - 1);
  float v = db[c];
  float4 v4 = make_float4(v, v, v, v);
  float4* o = (float4*)(out + (size_t)row * TT);
#pragma unroll
  for (int q = 0; q < 8; q++) o[q * 256 + threadIdx.x] = v4;
}

// ---------------- Pass E2: scatter — sig dot + rank-1 update per selected ----------
__global__ void pass_e2(const float* __restrict__ x, const float* __restrict__ uw,
                        const float* __restrict__ ub, const float* __restrict__ dw,
                        const int* __restrict__ selidx, const float* __restrict__ selval,
                        const int* __restrict__ selcnt, float* __restrict__ out) {
  int b = blockIdx.y, j = blockIdx.x;
  if (j >= selcnt[b]) return;
  int idx = selidx[b * KMAX + j];
  float val = selval[b * KMAX + j];
  int h = idx >> 13, t = idx & (TT - 1);
  int c = threadIdx.x;  // 64 threads: lanes handle c and c+64
  const float* xb = x + (size_t)b * CC * TT;
  float p = xb[(size_t)c * TT + t] * uw[h * CC + c] +
            xb[(size_t)(c + 64) * TT + t] * uw[h * CC + c + 64];
#pragma unroll
  for (int m = 1; m < 64; m <<= 1) p += __shfl_xor(p, m);
  float sig = p + ub[h];
  float g = sig * val;
  atomicAdd(&out[((size_t)b * CC + c) * TT + t], g * dw[c * HH + h]);
  atomicAdd(&out[((size_t)b * CC + c + 64) * TT + t], g * dw[(c + 64) * HH + h]);
}

extern "C" void kernel_launch(void* const* d_in, const int* in_sizes, int n_in,
                              void* d_out, int out_size, void* d_ws, size_t ws_size,
                              hipStream_t stream) {
  const float* x = (const float*)d_in[0];
  const float* uw = (const float*)d_in[1];
  const float* ub = (const float*)d_in[2];
  const float* sw = (const float*)d_in[3];
  const float* sb = (const float*)d_in[4];
  const float* dw = (const float*)d_in[5];
  const float* db = (const float*)d_in[6];
  const int* kptr = (const int*)d_in[7];
  float* out = (float*)d_out;
  char* ws = (char*)d_ws;

  int* hist = (int*)(ws + OFF_HIST);
  double* sumexp = (double*)(ws + OFF_SUMEXP);
  int* candcnt = (int*)(ws + OFF_CANDCNT);
  int* hotcnt = (int*)(ws + OFF_HOTCNT);
  float* tau = (float*)(ws + OFF_TAU);
  int* selcnt = (int*)(ws + OFF_SELCNT);
  float* cellmax = (float*)(ws + OFF_CELLMAX);
  int* hotlist = (int*)(ws + OFF_HOTLIST);
  double* candval = (double*)(ws + OFF_CANDVAL);
  int* candidx = (int*)(ws + OFF_CANDIDX);
  int* selidx = (int*)(ws + OFF_SELIDX);
  float* selval = (float*)(ws + OFF_SELVAL);

  (void)hipMemsetAsync(d_ws, 0, ZERO_BYTES, stream);
  pass_a<<<dim3(64, 4, 32), 256, 0, stream>>>(x, sw, sb, cellmax, hist, sumexp);
  pass_b<<<32, 256, 0, stream>>>(hist, tau, kptr);
  pass_c1<<<8192, 256, 0, stream>>>(cellmax, tau, hotcnt, hotlist);
  pass_c2<<<HOTCAP, 64, 0, stream>>>(x, sw, sb, tau, hotcnt, hotlist, candcnt, candval,
                                     candidx);
  pass_d<<<32, 256, 0, stream>>>(candcnt, candval, candidx, sumexp, kptr, selidx, selval,
                                 selcnt);
  pass_e1<<<BB * CC, 256, 0, stream>>>(db, out);
  pass_e2<<<dim3(KMAX, BB), 64, 0, stream>>>(x, uw, ub, dw, selidx, selval, selcnt, out);
}

// Round 4
// 1132.143 us; speedup vs baseline: 5.3907x; 1.0898x over previous
//
#include <hip/hip_runtime.h>
#include <hip/hip_bf16.h>
#include <math.h>

#define BB 32
#define CC 128
#define HH 512
#define TT 8192
#define KMAX 512

#define NBIN 2048
#define CANDCAP 4096
#define HOTCAP 32768
#define TILES 2048
#define TLCAP 256
// tau ~= 0.83; floor 0.6 keeps ~17k hist entries/batch (33x over K) -> ~0.5M atomics.
#define HFLOOR 0.6f
#define BW (0.875f / 2048.0f)
#define INVBW (2048.0f / 0.875f)
// bf16-MFMA sal noise: sigma ~2.6e-4, worst-case ~3e-3. Margins:
#define DELTA_C2 6e-3f   // candidate slack vs tau (fp64-verified values)
#define DELTA_C1 1.2e-2f // hot-cell slack: candidate slack + bf16 cellmax noise

// ---- fast-path workspace layout (bytes) ----
#define N_HIST 0              // int[32][2048]   (zeroed)
#define N_SUMEXP 262144       // double[32]      (zeroed)
#define N_CANDCNT 262400      // int[32]         (zeroed)
#define N_TILECNT 262528      // int[2048]       (zeroed)
#define N_ZERO 270720
#define N_TAU 270848
#define N_SELCNT 270976
#define N_CELLMAX 271360      // float[2097152]
#define N_TLIST 8659968       // int[2048*256]
#define N_CANDVAL 10757120    // double[32*4096]
#define N_CANDIDX 11805696    // int[32*4096]
#define N_SELIDX 12329984     // int[32*512]
#define N_SELVAL 12395520     // float[32*512]
#define N_SWB 12461056        // short[512*128]
#define N_XSW 12592128        // short[32*8192*128]
#define N_NEED 79700992

// ---- slow-path (R3) workspace layout ----
#define O_HIST 0
#define O_SUMEXP 262144
#define O_CANDCNT 262400
#define O_HOTCNT 262528
#define O_ZERO 262656
#define O_TAU 262656
#define O_SELCNT 262784
#define O_CELLMAX 263168
#define O_HOTLIST 8651776
#define O_CANDVAL 8782848
#define O_CANDIDX 9831424
#define O_SELIDX 10355712
#define O_SELVAL 10421248

typedef __attribute__((ext_vector_type(8))) short short8;
typedef __attribute__((ext_vector_type(16))) float f32x16;

__device__ __forceinline__ void dma16(const void* g, void* l) {
  __builtin_amdgcn_global_load_lds(
      (const __attribute__((address_space(1))) unsigned int*)(g),
      (__attribute__((address_space(3))) unsigned int*)(l), 16, 0, 0);
}

// ---------------- prep_w: sw fp32 -> swb bf16, row-swizzled -------------------------
// swizzle: within row h (128 shorts), 8-short block j stored at block (j ^ (h&15)).
__global__ void prep_w(const float* __restrict__ sw, short* __restrict__ swb) {
  int id = blockIdx.x * 256 + threadIdx.x;  // 8192 = 512h x 16 blocks
  int h = id >> 4, jb = id & 15;
  const float* src = sw + (size_t)h * CC + jb * 8;
  float4 f0 = *(const float4*)(src);
  float4 f1 = *(const float4*)(src + 4);
  union { __hip_bfloat162 h2; unsigned u; } p0, p1, p2, p3;
  p0.h2 = __float22bfloat162_rn(make_float2(f0.x, f0.y));
  p1.h2 = __float22bfloat162_rn(make_float2(f0.z, f0.w));
  p2.h2 = __float22bfloat162_rn(make_float2(f1.x, f1.y));
  p3.h2 = __float22bfloat162_rn(make_float2(f1.z, f1.w));
  int blk = jb ^ (h & 15);
  *(uint4*)(swb + (size_t)h * CC + (blk << 3)) = make_uint4(p0.u, p1.u, p2.u, p3.u);
}

// ---------------- prep_xt: x [b][c][t] fp32 -> xsw [b][t][c] bf16 row-swizzled ------
// grid (64 t-tiles, 32 b), 256 thr. LDS fp32 tile with 4-dword XOR swizzle:
//   addr(t,c) = t*128 + (((c>>2) ^ (t&31))<<2) + (c&3)
__global__ __launch_bounds__(256) void prep_xt(const float* __restrict__ x,
                                               short* __restrict__ xsw) {
  __shared__ float Lt[128 * 128];
  int tid = threadIdx.x;
  int b = blockIdx.y, t0g = blockIdx.x * 128;
  const float* xb = x + (size_t)b * CC * TT;
  int cq = tid >> 5, tq = tid & 31, t0 = tq * 4;
#pragma unroll
  for (int p = 0; p < 4; p++) {
    int c0 = p * 32 + cq * 4;
    float r0[4], r1[4], r2[4], r3[4];
    *(float4*)r0 = *(const float4*)(xb + (size_t)(c0 + 0) * TT + t0g + t0);
    *(float4*)r1 = *(const float4*)(xb + (size_t)(c0 + 1) * TT + t0g + t0);
    *(float4*)r2 = *(const float4*)(xb + (size_t)(c0 + 2) * TT + t0g + t0);
    *(float4*)r3 = *(const float4*)(xb + (size_t)(c0 + 3) * TT + t0g + t0);
#pragma unroll
    for (int j = 0; j < 4; j++) {
      int t = t0 + j;
      int addr = t * 128 + ((((c0 >> 2) ^ (t & 31)) << 2));
      float4 v = make_float4(r0[j], r1[j], r2[j], r3[j]);
      *(float4*)&Lt[addr] = v;
    }
  }
  __syncthreads();
  int t = tid >> 1, ch = (tid & 1) * 64;
  short* dst = xsw + ((size_t)b * TT + t0g + t) * CC;
#pragma unroll
  for (int j = 0; j < 8; j++) {
    int c0 = ch + j * 8;
    float4 f0 = *(float4*)&Lt[t * 128 + ((((c0 >> 2) ^ (t & 31)) << 2))];
    float4 f1 = *(float4*)&Lt[t * 128 + (((((c0 + 4) >> 2) ^ (t & 31)) << 2))];
    union { __hip_bfloat162 h2; unsigned u; } p0, p1, p2, p3;
    p0.h2 = __float22bfloat162_rn(make_float2(f0.x, f0.y));
    p1.h2 = __float22bfloat162_rn(make_float2(f0.z, f0.w));
    p2.h2 = __float22bfloat162_rn(make_float2(f1.x, f1.y));
    p3.h2 = __float22bfloat162_rn(make_float2(f1.z, f1.w));
    int blk = (c0 >> 3) ^ (t & 15);
    *(uint4*)(dst + (blk << 3)) = make_uint4(p0.u, p1.u, p2.u, p3.u);
  }
}

// ---------------- pass_a_fast: DMA-staged bf16 MFMA GEMM + stats --------------------
// grid (256, 32): bx = blockIdx.x>>2, by = blockIdx.x&3 (by fastest -> X-tile sharers
// co-resident -> L2 hits). Staging = pure global_load_lds 16B DMA (layout pre-swizzled).
__global__ __launch_bounds__(256) void pass_a_fast(const short* __restrict__ xsw,
                                                   const short* __restrict__ swb,
                                                   const float* __restrict__ sb,
                                                   float* __restrict__ cellmax,
                                                   int* __restrict__ hist,
                                                   double* __restrict__ sumexp) {
  __shared__ short Ws[128 * 128];
  __shared__ short Xs[128 * 128];
  __shared__ float sbs[128];
  int tid = threadIdx.x;
  int b = blockIdx.y;
  int bx = blockIdx.x >> 2, by = blockIdx.x & 3;
  int h0 = by * 128;
  int w = tid >> 6, lane = tid & 63, m = lane & 31, u = lane >> 5;

  const char* xtile = (const char*)xsw + ((size_t)b * TT + (size_t)bx * 128) * CC * 2;
  const char* wtile = (const char*)swb + (size_t)h0 * CC * 2;
  char* XsB = (char*)Xs;
  char* WsB = (char*)Ws;
#pragma unroll
  for (int k = 0; k < 8; k++) {
    int off = (w * 8 + k) * 1024;
    dma16(xtile + off + lane * 16, XsB + off);
    dma16(wtile + off + lane * 16, WsB + off);
  }
  if (tid < 128) sbs[tid] = sb[h0 + tid];
  __syncthreads();

  f32x16 acc0, acc1, acc2, acc3;
#pragma unroll
  for (int r = 0; r < 16; r++) { acc0[r] = 0.f; acc1[r] = 0.f; acc2[r] = 0.f; acc3[r] = 0.f; }
  const short* wrow = &Ws[(w * 32 + m) * 128];
  const short* xrow = &Xs[m * 128];
#pragma unroll
  for (int kc = 0; kc < 8; kc++) {
    int pc = ((((kc << 1) | u) ^ (m & 15)) << 3);
    short8 af = *(const short8*)(wrow + pc);
    short8 b0 = *(const short8*)(xrow + 0 * 32 * 128 + pc);
    short8 b1 = *(const short8*)(xrow + 1 * 32 * 128 + pc);
    short8 b2 = *(const short8*)(xrow + 2 * 32 * 128 + pc);
    short8 b3 = *(const short8*)(xrow + 3 * 32 * 128 + pc);
    acc0 = __builtin_amdgcn_mfma_f32_32x32x16_bf16(af, b0, acc0, 0, 0, 0);
    acc1 = __builtin_amdgcn_mfma_f32_32x32x16_bf16(af, b1, acc1, 0, 0, 0);
    acc2 = __builtin_amdgcn_mfma_f32_32x32x16_bf16(af, b2, acc2, 0, 0, 0);
    acc3 = __builtin_amdgcn_mfma_f32_32x32x16_bf16(af, b3, acc3, 0, 0, 0);
  }

  float tmax = -1e30f;
  float se = 0.f;
#define EPI(ACC)                                                              \
  {                                                                           \
    _Pragma("unroll") for (int g = 0; g < 4; g++) {                           \
      float bias4[4];                                                         \
      *(float4*)bias4 = *(float4*)&sbs[w * 32 + g * 8 + u * 4];               \
      _Pragma("unroll") for (int q = 0; q < 4; q++) {                         \
        float s = ACC[g * 4 + q] + bias4[q];                                  \
        tmax = fmaxf(tmax, s);                                                \
        se += __expf(s);                                                      \
        if (s >= HFLOOR) {                                                    \
          int bin = (int)((s - HFLOOR) * INVBW);                              \
          if (bin > NBIN - 1) bin = NBIN - 1;                                 \
          atomicAdd(&hist[b * NBIN + bin], 1);                                \
        }                                                                     \
      }                                                                       \
    }                                                                         \
  }
  EPI(acc0) EPI(acc1) EPI(acc2) EPI(acc3)
#undef EPI

  int cid = ((b * 4 + by) * 64 + bx) * 256 + tid;
  cellmax[cid] = tmax;
  double sed = (double)se;
#pragma unroll
  for (int mm = 1; mm < 64; mm <<= 1) sed += __shfl_xor(sed, mm);
  if ((tid & 63) == 0) atomicAdd(&sumexp[b], sed);
}

// ---------------- pass_b: per-batch threshold tau from histogram --------------------
__global__ void pass_b(const int* __restrict__ hist, float* __restrict__ tau,
                       const int* __restrict__ kptr) {
  __shared__ int hsh[NBIN];
  int b = blockIdx.x;
  for (int i = threadIdx.x; i < NBIN; i += blockDim.x) hsh[i] = hist[b * NBIN + i];
  __syncthreads();
  if (threadIdx.x == 0) {
    int k = kptr[0];
    if (k < 1) k = 1;
    if (k > KMAX) k = KMAX;
    long cum = 0;
    float tv = HFLOOR;
    for (int i = NBIN - 1; i >= 0; i--) {
      cum += hsh[i];
      if (cum >= k) { tv = HFLOOR + i * BW; break; }
    }
    tau[b] = tv;
  }
}

// ---------------- pass_c1_fast: compact hot cells into per-(b,bx)-tile lists --------
__global__ void pass_c1_fast(const float* __restrict__ cellmax, const float* __restrict__ tau,
                             int* __restrict__ tilecnt, int* __restrict__ tlist) {
  int i = blockIdx.x * blockDim.x + threadIdx.x;  // i == cid
  float v = cellmax[i];
  int b = i >> 16;
  if (v >= tau[b] - DELTA_C1) {
    int tile = (b << 6) | ((i >> 8) & 63);
    int pos = atomicAdd(&tilecnt[tile], 1);
    if (pos < TLCAP) tlist[tile * TLCAP + pos] = i;
  }
}

// ---------------- pass_c2_fast: tiled fp64 recompute of hot cells -------------------
// One block per (b, t-tile). Stage fp32 x tile coalesced into LDS with nt-rotation:
//   addr(c, t=nt*32+m) = c*132 + nt*32 + (((m>>2 + nt)&7)<<2) + (m&3)
// -> the 4 simultaneous column reads of a cell-wave land in 4 distinct banks.
__global__ __launch_bounds__(256) void pass_c2_fast(
    const float* __restrict__ x, const float* __restrict__ sw,
    const float* __restrict__ sb, const float* __restrict__ tau,
    const int* __restrict__ tilecnt, const int* __restrict__ tlist,
    int* __restrict__ candcnt, double* __restrict__ candval, int* __restrict__ candidx) {
  __shared__ float Xt[128 * 132];
  int tile = blockIdx.x;
  int b = tile >> 6, bx = tile & 63;
  int cnt = tilecnt[tile];
  if (cnt <= 0) return;
  if (cnt > TLCAP) cnt = TLCAP;
  int tid = threadIdx.x;
  {
    int cq = tid >> 5, tq = tid & 31;
    int t4 = tq * 4, snt = t4 >> 5, sa = (t4 >> 2) & 7;
    int sdst = snt * 32 + (((sa + snt) & 7) << 2);
    const float* xb = x + (size_t)b * CC * TT + bx * 128;
#pragma unroll
    for (int p = 0; p < 16; p++) {
      int c = p * 8 + cq;
      *(float4*)&Xt[c * 132 + sdst] = *(const float4*)(xb + (size_t)c * TT + t4);
    }
  }
  __syncthreads();
  int wv = tid >> 6, lane = tid & 63;
  float tmb = tau[b] - DELTA_C2;
  for (int s = wv; s < cnt; s += 4) {
    int cid = tlist[tile * TLCAP + s];
    int by = (cid >> 14) & 3;
    int ta = cid & 255;
    int w = ta >> 6, lc = ta & 63, m = lc & 31, u = lc >> 5;
    int nt = lane >> 4, r = lane & 15;
    int h = by * 128 + w * 32 + (r >> 2) * 8 + (r & 3) + 4 * u;
    int t = bx * 128 + nt * 32 + m;
    const float* swr = sw + (size_t)h * CC;
    int xoff = nt * 32 + (((((m >> 2) + nt) & 7)) << 2) + (m & 3);
    double a0 = 0.0, a1 = 0.0;
#pragma unroll 4
    for (int c = 0; c < CC; c += 2) {
      a0 = fma((double)Xt[c * 132 + xoff], (double)swr[c], a0);
      a1 = fma((double)Xt[(c + 1) * 132 + xoff], (double)swr[c + 1], a1);
    }
    double acc = a0 + a1 + (double)sb[h];
    if (acc >= (double)tmb) {
      int pos = atomicAdd(&candcnt[b], 1);
      if (pos < CANDCAP) {
        candval[b * CANDCAP + pos] = acc;
        candidx[b * CANDCAP + pos] = h * TT + t;
      }
    }
  }
}

// ---------------- pass_d: exact top-k among candidates ------------------------------
__global__ void pass_d(const int* __restrict__ candcnt, const double* __restrict__ candval,
                       const int* __restrict__ candidx, const double* __restrict__ sumexp,
                       const int* __restrict__ kptr, int* __restrict__ selidx,
                       float* __restrict__ selval, int* __restrict__ selcnt) {
  __shared__ double sv[CANDCAP];
  __shared__ int si[CANDCAP];
  int b = blockIdx.x;
  int n = candcnt[b];
  if (n > CANDCAP) n = CANDCAP;
  int k = kptr[0];
  if (k < 0) k = 0;
  if (k > KMAX) k = KMAX;
  for (int i = threadIdx.x; i < n; i += blockDim.x) {
    sv[i] = candval[b * CANDCAP + i];
    si[i] = candidx[b * CANDCAP + i];
  }
  __syncthreads();
  double S = sumexp[b];
  for (int i = threadIdx.x; i < n; i += blockDim.x) {
    double vi = sv[i];
    int ii = si[i];
    int rank = 0;
    for (int q = 0; q < n; q++) {
      double vq = sv[q];
      rank += (vq > vi) || (vq == vi && si[q] < ii);
    }
    if (rank < k) {
      selidx[b * KMAX + rank] = ii;
      selval[b * KMAX + rank] = (float)(exp(vi) / S);
    }
  }
  if (threadIdx.x == 0) selcnt[b] = n < k ? n : k;
}

// ---------------- pass_e1: out = down_b broadcast -----------------------------------
__global__ void pass_e1(const float* __restrict__ db, float* __restrict__ out) {
  int row = blockIdx.x;  // b*C + c
  int c = row & (CC - 1);
  float v = db[c];
  float4 v4 = make_float4(v, v, v, v);
  float4* o = (float4*)(out + (size_t)row * TT);
#pragma unroll
  for (int q = 0; q < 8; q++) o[q * 256 + threadIdx.x] = v4;
}

// ---------------- pass_e2: scatter — sig dot + rank-1 update per selected -----------
__global__ void pass_e2(const float* __restrict__ x, const float* __restrict__ uw,
                        const float* __restrict__ ub, const float* __restrict__ dw,
                        const int* __restrict__ selidx, const float* __restrict__ selval,
                        const int* __restrict__ selcnt, float* __restrict__ out) {
  int b = blockIdx.y, j = blockIdx.x;
  if (j >= selcnt[b]) return;
  int idx = selidx[b * KMAX + j];
  float val = selval[b * KMAX + j];
  int h = idx >> 13, t = idx & (TT - 1);
  int c = threadIdx.x;
  const float* xb = x + (size_t)b * CC * TT;
  float p = xb[(size_t)c * TT + t] * uw[h * CC + c] +
            xb[(size_t)(c + 64) * TT + t] * uw[h * CC + c + 64];
#pragma unroll
  for (int m = 1; m < 64; m <<= 1) p += __shfl_xor(p, m);
  float sig = p + ub[h];
  float g = sig * val;
  atomicAdd(&out[((size_t)b * CC + c) * TT + t], g * dw[c * HH + h]);
  atomicAdd(&out[((size_t)b * CC + c + 64) * TT + t], g * dw[(c + 64) * HH + h]);
}

// ================= slow-path (R3, proven) kernels for small ws ======================
__global__ __launch_bounds__(256) void pass_a_slow(const float* __restrict__ x,
                                                   const float* __restrict__ sw,
                                                   const float* __restrict__ sb,
                                                   float* __restrict__ cellmax,
                                                   int* __restrict__ hist,
                                                   double* __restrict__ sumexp) {
  __shared__ short Ws[128 * 128];
  __shared__ short Xs[128 * 128];
  __shared__ float sbs[128];
  int tid = threadIdx.x;
  int b = blockIdx.z, by = blockIdx.y, bx = blockIdx.x;
  int h0 = by * 128, t0g = bx * 128;
  const float* xb = x + (size_t)b * CC * TT;
  {
    int cq = tid >> 5, tq = tid & 31;
    int t0 = tq * 4;
#pragma unroll
    for (int p = 0; p < 4; p++) {
      int c0 = p * 32 + cq * 4;
      float r0[4], r1[4], r2[4], r3[4];
      *(float4*)r0 = *(const float4*)(xb + (size_t)(c0 + 0) * TT + t0g + t0);
      *(float4*)r1 = *(const float4*)(xb + (size_t)(c0 + 1) * TT + t0g + t0);
      *(float4*)r2 = *(const float4*)(xb + (size_t)(c0 + 2) * TT + t0g + t0);
      *(float4*)r3 = *(const float4*)(xb + (size_t)(c0 + 3) * TT + t0g + t0);
#pragma unroll
      for (int j = 0; j < 4; j++) {
        int t = t0 + j;
        int addr = t * 128 + ((((c0 >> 3) ^ (t & 15)) << 3) | (c0 & 7));
        union { __hip_bfloat162 h; unsigned int u; } a0, a1;
        a0.h = __float22bfloat162_rn(make_float2(r0[j], r1[j]));
        a1.h = __float22bfloat162_rn(make_float2(r2[j], r3[j]));
        *(uint2*)&Xs[addr] = make_uint2(a0.u, a1.u);
      }
    }
  }
  {
    int hh = tid >> 1, c4 = (tid & 1) << 2;
#pragma unroll
    for (int k = 0; k < 16; k++) {
      int c0 = k * 8 + c4;
      float r[4];
      *(float4*)r = *(const float4*)(sw + (size_t)(h0 + hh) * CC + c0);
      int addr = hh * 128 + ((((c0 >> 3) ^ (hh & 15)) << 3) | (c0 & 7));
      union { __hip_bfloat162 h; unsigned int u; } a0, a1;
      a0.h = __float22bfloat162_rn(make_float2(r[0], r[1]));
      a1.h = __float22bfloat162_rn(make_float2(r[2], r[3]));
      *(uint2*)&Ws[addr] = make_uint2(a0.u, a1.u);
    }
  }
  if (tid < 128) sbs[tid] = sb[h0 + tid];
  __syncthreads();
  int w = tid >> 6, lane = tid & 63, m = lane & 31, u = lane >> 5;
  f32x16 acc0, acc1, acc2, acc3;
#pragma unroll
  for (int r = 0; r < 16; r++) { acc0[r] = 0.f; acc1[r] = 0.f; acc2[r] = 0.f; acc3[r] = 0.f; }
  const short* wrow = &Ws[(w * 32 + m) * 128];
  const short* xrow = &Xs[m * 128];
#pragma unroll
  for (int kc = 0; kc < 8; kc++) {
    int pc = ((((kc << 1) | u) ^ (m & 15)) << 3);
    short8 af = *(const short8*)(wrow + pc);
    short8 b0 = *(const short8*)(xrow + 0 * 32 * 128 + pc);
    short8 b1 = *(const short8*)(xrow + 1 * 32 * 128 + pc);
    short8 b2 = *(const short8*)(xrow + 2 * 32 * 128 + pc);
    short8 b3 = *(const short8*)(xrow + 3 * 32 * 128 + pc);
    acc0 = __builtin_amdgcn_mfma_f32_32x32x16_bf16(af, b0, acc0, 0, 0, 0);
    acc1 = __builtin_amdgcn_mfma_f32_32x32x16_bf16(af, b1, acc1, 0, 0, 0);
    acc2 = __builtin_amdgcn_mfma_f32_32x32x16_bf16(af, b2, acc2, 0, 0, 0);
    acc3 = __builtin_amdgcn_mfma_f32_32x32x16_bf16(af, b3, acc3, 0, 0, 0);
  }
  float tmax = -1e30f;
  float se = 0.f;
#define EPI(ACC)                                                              \
  {                                                                           \
    _Pragma("unroll") for (int g = 0; g < 4; g++) {                           \
      float bias4[4];                                                         \
      *(float4*)bias4 = *(float4*)&sbs[w * 32 + g * 8 + u * 4];               \
      _Pragma("unroll") for (int q = 0; q < 4; q++) {                         \
        float s = ACC[g * 4 + q] + bias4[q];                                  \
        tmax = fmaxf(tmax, s);                                                \
        se += __expf(s);                                                      \
        if (s >= HFLOOR) {                                                    \
          int bin = (int)((s - HFLOOR) * INVBW);                              \
          if (bin > NBIN - 1) bin = NBIN - 1;                                 \
          atomicAdd(&hist[b * NBIN + bin], 1);                                \
        }                                                                     \
      }                                                                       \
    }                                                                         \
  }
  EPI(acc0) EPI(acc1) EPI(acc2) EPI(acc3)
#undef EPI
  int cid = ((b * 4 + by) * 64 + bx) * 256 + tid;
  cellmax[cid] = tmax;
  double sed = (double)se;
#pragma unroll
  for (int mm = 1; mm < 64; mm <<= 1) sed += __shfl_xor(sed, mm);
  if ((tid & 63) == 0) atomicAdd(&sumexp[b], sed);
}

__global__ void pass_c1_slow(const float* __restrict__ cellmax, const float* __restrict__ tau,
                             int* __restrict__ hotcnt, int* __restrict__ hotlist) {
  int i = blockIdx.x * blockDim.x + threadIdx.x;
  float v = cellmax[i];
  int b = i >> 16;
  if (v >= tau[b] - DELTA_C1) {
    int pos = atomicAdd(hotcnt, 1);
    if (pos < HOTCAP) hotlist[pos] = i;
  }
}

__global__ void pass_c2_slow(const float* __restrict__ x, const float* __restrict__ sw,
                             const float* __restrict__ sb, const float* __restrict__ tau,
                             const int* __restrict__ hotcnt, const int* __restrict__ hotlist,
                             int* __restrict__ candcnt, double* __restrict__ candval,
                             int* __restrict__ candidx) {
  int j = blockIdx.x;
  int n = hotcnt[0];
  if (n > HOTCAP) n = HOTCAP;
  if (j >= n) return;
  int cid = hotlist[j];
  int b = cid >> 16, by = (cid >> 14) & 3, bx = (cid >> 8) & 63;
  int ta = cid & 255;
  int w = ta >> 6, lane = ta & 63, m = lane & 31, u = lane >> 5;
  int e = threadIdx.x;
  int nt = e >> 4, r = e & 15;
  int h = by * 128 + w * 32 + (r >> 2) * 8 + (r & 3) + 4 * u;
  int t = bx * 128 + nt * 32 + m;
  const float* xb = x + (size_t)b * CC * TT;
  double acc = 0.0;
#pragma unroll 8
  for (int c = 0; c < CC; c++)
    acc += (double)xb[(size_t)c * TT + t] * (double)sw[h * CC + c];
  acc += (double)sb[h];
  float tm = tau[b] - DELTA_C2;
  if (acc >= (double)tm) {
    int pos = atomicAdd(&candcnt[b], 1);
    if (pos < CANDCAP) {
      candval[b * CANDCAP + pos] = acc;
      candidx[b * CANDCAP + pos] = h * TT + t;
    }
  }
}

extern "C" void kernel_launch(void* const* d_in, const int* in_sizes, int n_in,
                              void* d_out, int out_size, void* d_ws, size_t ws_size,
                              hipStream_t stream) {
  const float* x = (const float*)d_in[0];
  const float* uw = (const float*)d_in[1];
  const float* ub = (const float*)d_in[2];
  const float* sw = (const float*)d_in[3];
  const float* sb = (const float*)d_in[4];
  const float* dw = (const float*)d_in[5];
  const float* db = (const float*)d_in[6];
  const int* kptr = (const int*)d_in[7];
  float* out = (float*)d_out;
  char* ws = (char*)d_ws;

  if (ws_size >= (size_t)N_NEED) {
    int* hist = (int*)(ws + N_HIST);
    double* sumexp = (double*)(ws + N_SUMEXP);
    int* candcnt = (int*)(ws + N_CANDCNT);
    int* tilecnt = (int*)(ws + N_TILECNT);
    float* tau = (float*)(ws + N_TAU);
    int* selcnt = (int*)(ws + N_SELCNT);
    float* cellmax = (float*)(ws + N_CELLMAX);
    int* tlist = (int*)(ws + N_TLIST);
    double* candval = (double*)(ws + N_CANDVAL);
    int* candidx = (int*)(ws + N_CANDIDX);
    int* selidx = (int*)(ws + N_SELIDX);
    float* selval = (float*)(ws + N_SELVAL);
    short* swb = (short*)(ws + N_SWB);
    short* xsw = (short*)(ws + N_XSW);

    (void)hipMemsetAsync(d_ws, 0, N_ZERO, stream);
    prep_w<<<32, 256, 0, stream>>>(sw, swb);
    prep_xt<<<dim3(64, 32), 256, 0, stream>>>(x, xsw);
    pass_a_fast<<<dim3(256, 32), 256, 0, stream>>>(xsw, swb, sb, cellmax, hist, sumexp);
    pass_b<<<32, 256, 0, stream>>>(hist, tau, kptr);
    pass_c1_fast<<<8192, 256, 0, stream>>>(cellmax, tau, tilecnt, tlist);
    pass_c2_fast<<<TILES, 256, 0, stream>>>(x, sw, sb, tau, tilecnt, tlist, candcnt,
                                            candval, candidx);
    pass_d<<<32, 256, 0, stream>>>(candcnt, candval, candidx, sumexp, kptr, selidx,
                                   selval, selcnt);
    pass_e1<<<BB * CC, 256, 0, stream>>>(db, out);
    pass_e2<<<dim3(KMAX, BB), 64, 0, stream>>>(x, uw, ub, dw, selidx, selval, selcnt, out);
  } else {
    int* hist = (int*)(ws + O_HIST);
    double* sumexp = (double*)(ws + O_SUMEXP);
    int* candcnt = (int*)(ws + O_CANDCNT);
    int* hotcnt = (int*)(ws + O_HOTCNT);
    float* tau = (float*)(ws + O_TAU);
    int* selcnt = (int*)(ws + O_SELCNT);
    float* cellmax = (float*)(ws + O_CELLMAX);
    int* hotlist = (int*)(ws + O_HOTLIST);
    double* candval = (double*)(ws + O_CANDVAL);
    int* candidx = (int*)(ws + O_CANDIDX);
    int* selidx = (int*)(ws + O_SELIDX);
    float* selval = (float*)(ws + O_SELVAL);

    (void)hipMemsetAsync(d_ws, 0, O_ZERO, stream);
    pass_a_slow<<<dim3(64, 4, 32), 256, 0, stream>>>(x, sw, sb, cellmax, hist, sumexp);
    pass_b<<<32, 256, 0, stream>>>(hist, tau, kptr);
    pass_c1_slow<<<8192, 256, 0, stream>>>(cellmax, tau, hotcnt, hotlist);
    pass_c2_slow<<<HOTCAP, 64, 0, stream>>>(x, sw, sb, tau, hotcnt, hotlist, candcnt,
                                            candval, candidx);
    pass_d<<<32, 256, 0, stream>>>(candcnt, candval, candidx, sumexp, kptr, selidx,
                                   selval, selcnt);
    pass_e1<<<BB * CC, 256, 0, stream>>>(db, out);
    pass_e2<<<dim3(KMAX, BB), 64, 0, stream>>>(x, uw, ub, dw, selidx, selval, selcnt, out);
  }
}

// Round 5
// 1028.684 us; speedup vs baseline: 5.9329x; 1.1006x over previous
//
#include <hip/hip_runtime.h>
#include <hip/hip_bf16.h>
#include <math.h>

#define BB 32
#define CC 128
#define HH 512
#define TT 8192
#define KMAX 512

#define NBIN 2048
#define CANDCAP 4096
#define HOTCAP 32768
#define TILES 2048
#define TLCAP 256
// tau ~= 0.83; floor 0.6 keeps ~17k hist entries/batch (33x over K) -> ~0.5M atomics.
#define HFLOOR 0.6f
#define BW (0.875f / 2048.0f)
#define INVBW (2048.0f / 0.875f)
// bf16-MFMA sal noise: sigma ~2.6e-4, worst-case ~3e-3. Margins:
#define DELTA_C2 6e-3f   // candidate slack vs tau (fp64-verified values)
#define DELTA_C1 1.2e-2f // hot-cell slack: candidate slack + bf16 cellmax noise

// ---- fast-path workspace layout (bytes) ----
#define N_HIST 0              // int[32][2048]   (zeroed)
#define N_SUMEXP 262144       // double[32]      (zeroed)
#define N_CANDCNT 262400      // int[32]         (zeroed)
#define N_TILECNT 262528      // int[2048]       (zeroed)
#define N_ZERO 270720
#define N_TAU 270848
#define N_SELCNT 270976
#define N_CELLMAX 271360      // float[2097152]
#define N_TLIST 8659968       // int[2048*256]
#define N_CANDVAL 10757120    // double[32*4096]
#define N_CANDIDX 11805696    // int[32*4096]
#define N_SELIDX 12329984     // int[32*512]
#define N_SELVAL 12395520     // float[32*512]
#define N_SWB 12461056        // short[512*128]  W in MFMA A-frag order
#define N_XF 12592128         // short[32*64*16384]  X in MFMA B-frag order
#define N_DWT 79700992        // float[512*128]  down_w transposed [h][c]
#define N_NEED 79963136

// ---- slow-path (R3) workspace layout ----
#define O_HIST 0
#define O_SUMEXP 262144
#define O_CANDCNT 262400
#define O_HOTCNT 262528
#define O_ZERO 262656
#define O_TAU 262656
#define O_SELCNT 262784
#define O_CELLMAX 263168
#define O_HOTLIST 8651776
#define O_CANDVAL 8782848
#define O_CANDIDX 9831424
#define O_SELIDX 10355712
#define O_SELVAL 10421248

typedef __attribute__((ext_vector_type(8))) short short8;
typedef __attribute__((ext_vector_type(16))) float f32x16;

// ===== Fragment layouts (derived from the verified R3 LDS kernel) =====
// A-frag (W): lane l=(m=l&31,u=l>>5) of wave w in by-slice holds sw[h=by*128+w*32+m][c=kc*16+u*8 .. +8]
//   swb short index = (by*4+w)*4096 + kc*512 + u*256 + m*8
// B-frag (X): lane l holds x[t=bx*128+nt*32+m][c=kc*16+u*8 .. +8] (bf16)
//   xf short index = (b*64+bx)*16384 + nt*4096 + kc*512 + u*256 + m*8
// Both are lane-contiguous: chunk_base + l*16 bytes -> coalesced dwordx4 loads.

// ---------------- prep_w: sw fp32 -> swb bf16 in A-frag order -----------------------
__global__ void prep_w(const float* __restrict__ sw, short* __restrict__ swb) {
  int i = blockIdx.x * 256 + threadIdx.x;  // 8192 chunks of 8 shorts
  int m = i & 31, u = (i >> 5) & 1, kc = (i >> 6) & 7, w = (i >> 9) & 3, by = i >> 11;
  int h = by * 128 + w * 32 + m;
  int c0 = kc * 16 + u * 8;
  float4 f0 = *(const float4*)(sw + (size_t)h * CC + c0);
  float4 f1 = *(const float4*)(sw + (size_t)h * CC + c0 + 4);
  union { __hip_bfloat162 h2; unsigned u; } p0, p1, p2, p3;
  p0.h2 = __float22bfloat162_rn(make_float2(f0.x, f0.y));
  p1.h2 = __float22bfloat162_rn(make_float2(f0.z, f0.w));
  p2.h2 = __float22bfloat162_rn(make_float2(f1.x, f1.y));
  p3.h2 = __float22bfloat162_rn(make_float2(f1.z, f1.w));
  *(uint4*)(swb + (size_t)i * 8) = make_uint4(p0.u, p1.u, p2.u, p3.u);
}

// ---------------- prep_dwt: dw [c][h] -> dwt [h][c] ---------------------------------
__global__ void prep_dwt(const float* __restrict__ dw, float* __restrict__ dwt) {
  int i = blockIdx.x * 256 + threadIdx.x;  // 65536
  int c = i & 127, h = i >> 7;
  dwt[(size_t)h * CC + c] = dw[(size_t)c * HH + h];
}

// ---------------- prep_xt: x [b][c][t] fp32 -> xf bf16 B-frag order -----------------
// grid (64 t-tiles, 32 b), 256 thr. LDS fp32 tile with 4-dword XOR swizzle:
//   addr(t,c) = t*128 + (((c>>2) ^ (t&31))<<2) + (c&3)
__global__ __launch_bounds__(256) void prep_xt(const float* __restrict__ x,
                                               short* __restrict__ xf) {
  __shared__ float Lt[128 * 128];
  int tid = threadIdx.x;
  int b = blockIdx.y, bx = blockIdx.x, t0g = bx * 128;
  const float* xb = x + (size_t)b * CC * TT;
  {
    int cq = tid >> 5, tq = tid & 31, t0 = tq * 4;
#pragma unroll
    for (int p = 0; p < 4; p++) {
      int c0 = p * 32 + cq * 4;
      float r0[4], r1[4], r2[4], r3[4];
      *(float4*)r0 = *(const float4*)(xb + (size_t)(c0 + 0) * TT + t0g + t0);
      *(float4*)r1 = *(const float4*)(xb + (size_t)(c0 + 1) * TT + t0g + t0);
      *(float4*)r2 = *(const float4*)(xb + (size_t)(c0 + 2) * TT + t0g + t0);
      *(float4*)r3 = *(const float4*)(xb + (size_t)(c0 + 3) * TT + t0g + t0);
#pragma unroll
      for (int j = 0; j < 4; j++) {
        int t = t0 + j;
        int addr = t * 128 + ((((c0 >> 2) ^ (t & 31)) << 2));
        *(float4*)&Lt[addr] = make_float4(r0[j], r1[j], r2[j], r3[j]);
      }
    }
  }
  __syncthreads();
  // output: thread = (nt, m, u); loop kc. t = nt*32+m, c0 = kc*16+u*8
  int u = tid & 1, m = (tid >> 1) & 31, nt = (tid >> 6) & 3;
  int t = nt * 32 + m;
  short* dst = xf + ((size_t)b * 64 + bx) * 16384 + nt * 4096 + u * 256 + m * 8;
#pragma unroll
  for (int kc = 0; kc < 8; kc++) {
    int c0 = kc * 16 + u * 8;
    float4 f0 = *(float4*)&Lt[t * 128 + ((((c0 >> 2) ^ (t & 31)) << 2))];
    float4 f1 = *(float4*)&Lt[t * 128 + (((((c0 + 4) >> 2) ^ (t & 31)) << 2))];
    union { __hip_bfloat162 h2; unsigned u; } p0, p1, p2, p3;
    p0.h2 = __float22bfloat162_rn(make_float2(f0.x, f0.y));
    p1.h2 = __float22bfloat162_rn(make_float2(f0.z, f0.w));
    p2.h2 = __float22bfloat162_rn(make_float2(f1.x, f1.y));
    p3.h2 = __float22bfloat162_rn(make_float2(f1.z, f1.w));
    *(uint4*)(dst + kc * 512) = make_uint4(p0.u, p1.u, p2.u, p3.u);
  }
}

// ---------------- pass_a_reg: register-direct bf16 MFMA GEMM + stats ----------------
// No LDS, no barriers: fragments loaded straight from global (pre-laid-out), manual
// 2-stage register pipeline over kc -> compiler emits fine-grained vmcnt(N) waits.
// XCD swizzle: bx=((id>>5)<<3)|(id&7), by=(id>>3)&3 -> 4 by-sharers of each bx land
// on one XCD within 24 dispatch slots (X HBM-fetched once per XCD).
__global__ __launch_bounds__(256) void pass_a_reg(const short* __restrict__ xf,
                                                  const short* __restrict__ swb,
                                                  const float* __restrict__ sb,
                                                  float* __restrict__ cellmax,
                                                  int* __restrict__ hist,
                                                  double* __restrict__ sumexp) {
  int tid = threadIdx.x;
  int w = tid >> 6, lane = tid & 63, m = lane & 31, u = lane >> 5;
  int id = blockIdx.x, b = blockIdx.y;
  int bx = ((id >> 5) << 3) | (id & 7);
  int by = (id >> 3) & 3;

  const short* wb_ = swb + (size_t)(by * 4 + w) * 4096 + u * 256 + m * 8;  // +kc*512
  const short* xb_ = xf + (size_t)(b * 64 + bx) * 16384 + u * 256 + m * 8; // +nt*4096+kc*512

  f32x16 acc0, acc1, acc2, acc3;
#pragma unroll
  for (int r = 0; r < 16; r++) { acc0[r] = 0.f; acc1[r] = 0.f; acc2[r] = 0.f; acc3[r] = 0.f; }

  short8 afr[2], bfr[2][4];
  afr[0] = *(const short8*)(wb_);
  bfr[0][0] = *(const short8*)(xb_);
  bfr[0][1] = *(const short8*)(xb_ + 4096);
  bfr[0][2] = *(const short8*)(xb_ + 8192);
  bfr[0][3] = *(const short8*)(xb_ + 12288);
#pragma unroll
  for (int kc = 0; kc < 8; kc++) {
    int cur = kc & 1, nxt = cur ^ 1;
    if (kc < 7) {
      const short* wn = wb_ + (kc + 1) * 512;
      const short* xn = xb_ + (kc + 1) * 512;
      afr[nxt] = *(const short8*)(wn);
      bfr[nxt][0] = *(const short8*)(xn);
      bfr[nxt][1] = *(const short8*)(xn + 4096);
      bfr[nxt][2] = *(const short8*)(xn + 8192);
      bfr[nxt][3] = *(const short8*)(xn + 12288);
    }
    acc0 = __builtin_amdgcn_mfma_f32_32x32x16_bf16(afr[cur], bfr[cur][0], acc0, 0, 0, 0);
    acc1 = __builtin_amdgcn_mfma_f32_32x32x16_bf16(afr[cur], bfr[cur][1], acc1, 0, 0, 0);
    acc2 = __builtin_amdgcn_mfma_f32_32x32x16_bf16(afr[cur], bfr[cur][2], acc2, 0, 0, 0);
    acc3 = __builtin_amdgcn_mfma_f32_32x32x16_bf16(afr[cur], bfr[cur][3], acc3, 0, 0, 0);
  }

  // epilogue: bias + max + exp + hist. C/D: col(t)=lane&31, row(h)=8g+q+4u
  int h0 = by * 128;
  float tmax = -1e30f;
  float se = 0.f;
#define EPI(ACC)                                                              \
  {                                                                           \
    _Pragma("unroll") for (int g = 0; g < 4; g++) {                           \
      float bias4[4];                                                         \
      *(float4*)bias4 = *(const float4*)&sb[h0 + w * 32 + g * 8 + u * 4];     \
      _Pragma("unroll") for (int q = 0; q < 4; q++) {                         \
        float s = ACC[g * 4 + q] + bias4[q];                                  \
        tmax = fmaxf(tmax, s);                                                \
        se += __expf(s);                                                      \
        if (s >= HFLOOR) {                                                    \
          int bin = (int)((s - HFLOOR) * INVBW);                              \
          if (bin > NBIN - 1) bin = NBIN - 1;                                 \
          atomicAdd(&hist[b * NBIN + bin], 1);                                \
        }                                                                     \
      }                                                                       \
    }                                                                         \
  }
  EPI(acc0) EPI(acc1) EPI(acc2) EPI(acc3)
#undef EPI

  int cid = ((b * 4 + by) * 64 + bx) * 256 + tid;
  cellmax[cid] = tmax;
  double sed = (double)se;
#pragma unroll
  for (int mm = 1; mm < 64; mm <<= 1) sed += __shfl_xor(sed, mm);
  if ((tid & 63) == 0) atomicAdd(&sumexp[b], sed);
}

// ---------------- pass_b: per-batch threshold tau from histogram (parallel) ---------
__global__ void pass_b(const int* __restrict__ hist, float* __restrict__ tau,
                       const int* __restrict__ kptr) {
  __shared__ int hsh[NBIN];
  __shared__ int ps[256];
  int b = blockIdx.x, tid = threadIdx.x;
  int part = 0;
#pragma unroll
  for (int j = 0; j < 8; j++) {
    int v = hist[b * NBIN + tid * 8 + j];
    hsh[tid * 8 + j] = v;
    part += v;
  }
  ps[tid] = part;
  __syncthreads();
  if (tid == 0) {
    int k = kptr[0];
    if (k < 1) k = 1;
    if (k > KMAX) k = KMAX;
    long cum = 0;
    float tv = HFLOOR;
    for (int i = 255; i >= 0; i--) {
      if (cum + ps[i] >= k) {
        long r = k - cum;
        long c2 = 0;
        for (int j = 7; j >= 0; j--) {
          c2 += hsh[i * 8 + j];
          if (c2 >= r) { tv = HFLOOR + (i * 8 + j) * BW; break; }
        }
        break;
      }
      cum += ps[i];
    }
    tau[b] = tv;
  }
}

// ---------------- pass_c1_fast: compact hot cells into per-(b,bx)-tile lists --------
__global__ void pass_c1_fast(const float* __restrict__ cellmax, const float* __restrict__ tau,
                             int* __restrict__ tilecnt, int* __restrict__ tlist) {
  int i = blockIdx.x * blockDim.x + threadIdx.x;  // i == cid
  float v = cellmax[i];
  int b = i >> 16;
  if (v >= tau[b] - DELTA_C1) {
    int tile = (b << 6) | ((i >> 8) & 63);
    int pos = atomicAdd(&tilecnt[tile], 1);
    if (pos < TLCAP) tlist[tile * TLCAP + pos] = i;
  }
}

// ---------------- pass_c2_fast: tiled fp64 recompute of hot cells -------------------
__global__ __launch_bounds__(256) void pass_c2_fast(
    const float* __restrict__ x, const float* __restrict__ sw,
    const float* __restrict__ sb, const float* __restrict__ tau,
    const int* __restrict__ tilecnt, const int* __restrict__ tlist,
    int* __restrict__ candcnt, double* __restrict__ candval, int* __restrict__ candidx) {
  __shared__ float Xt[128 * 132];
  int tile = blockIdx.x;
  int b = tile >> 6, bx = tile & 63;
  int cnt = tilecnt[tile];
  if (cnt <= 0) return;
  if (cnt > TLCAP) cnt = TLCAP;
  int tid = threadIdx.x;
  {
    int cq = tid >> 5, tq = tid & 31;
    int t4 = tq * 4, snt = t4 >> 5, sa = (t4 >> 2) & 7;
    int sdst = snt * 32 + (((sa + snt) & 7) << 2);
    const float* xb = x + (size_t)b * CC * TT + bx * 128;
#pragma unroll
    for (int p = 0; p < 16; p++) {
      int c = p * 8 + cq;
      *(float4*)&Xt[c * 132 + sdst] = *(const float4*)(xb + (size_t)c * TT + t4);
    }
  }
  __syncthreads();
  int wv = tid >> 6, lane = tid & 63;
  float tmb = tau[b] - DELTA_C2;
  for (int s = wv; s < cnt; s += 4) {
    int cid = tlist[tile * TLCAP + s];
    int by = (cid >> 14) & 3;
    int ta = cid & 255;
    int w = ta >> 6, lc = ta & 63, m = lc & 31, u = lc >> 5;
    int nt = lane >> 4, r = lane & 15;
    int h = by * 128 + w * 32 + (r >> 2) * 8 + (r & 3) + 4 * u;
    int t = bx * 128 + nt * 32 + m;
    const float* swr = sw + (size_t)h * CC;
    int xoff = nt * 32 + (((((m >> 2) + nt) & 7)) << 2) + (m & 3);
    double a0 = 0.0, a1 = 0.0;
#pragma unroll 4
    for (int c = 0; c < CC; c += 2) {
      a0 = fma((double)Xt[c * 132 + xoff], (double)swr[c], a0);
      a1 = fma((double)Xt[(c + 1) * 132 + xoff], (double)swr[c + 1], a1);
    }
    double acc = a0 + a1 + (double)sb[h];
    if (acc >= (double)tmb) {
      int pos = atomicAdd(&candcnt[b], 1);
      if (pos < CANDCAP) {
        candval[b * CANDCAP + pos] = acc;
        candidx[b * CANDCAP + pos] = h * TT + t;
      }
    }
  }
}

// ---------------- pass_d: exact top-k among candidates ------------------------------
__global__ void pass_d(const int* __restrict__ candcnt, const double* __restrict__ candval,
                       const int* __restrict__ candidx, const double* __restrict__ sumexp,
                       const int* __restrict__ kptr, int* __restrict__ selidx,
                       float* __restrict__ selval, int* __restrict__ selcnt) {
  __shared__ double sv[CANDCAP];
  __shared__ int si[CANDCAP];
  int b = blockIdx.x;
  int n = candcnt[b];
  if (n > CANDCAP) n = CANDCAP;
  int k = kptr[0];
  if (k < 0) k = 0;
  if (k > KMAX) k = KMAX;
  for (int i = threadIdx.x; i < n; i += blockDim.x) {
    sv[i] = candval[b * CANDCAP + i];
    si[i] = candidx[b * CANDCAP + i];
  }
  __syncthreads();
  double S = sumexp[b];
  for (int i = threadIdx.x; i < n; i += blockDim.x) {
    double vi = sv[i];
    int ii = si[i];
    int rank = 0;
    for (int q = 0; q < n; q++) {
      double vq = sv[q];
      rank += (vq > vi) || (vq == vi && si[q] < ii);
    }
    if (rank < k) {
      selidx[b * KMAX + rank] = ii;
      selval[b * KMAX + rank] = (float)(exp(vi) / S);
    }
  }
  if (threadIdx.x == 0) selcnt[b] = n < k ? n : k;
}

// ---------------- pass_e1: out = down_b broadcast -----------------------------------
__global__ void pass_e1(const float* __restrict__ db, float* __restrict__ out) {
  int row = blockIdx.x;  // b*C + c
  int c = row & (CC - 1);
  float v = db[c];
  float4 v4 = make_float4(v, v, v, v);
  float4* o = (float4*)(out + (size_t)row * TT);
#pragma unroll
  for (int q = 0; q < 8; q++) o[q * 256 + threadIdx.x] = v4;
}

// ---------------- pass_e2_fast: scatter using bf16 xf gather + dwt ------------------
// sig from bf16 x: err ~5e-4 abs; out err ~5e-4*val(5e-7)*dw(0.02) ~ 6e-12 << tol.
__global__ void pass_e2_fast(const short* __restrict__ xf, const float* __restrict__ uw,
                             const float* __restrict__ ub, const float* __restrict__ dwt,
                             const int* __restrict__ selidx, const float* __restrict__ selval,
                             const int* __restrict__ selcnt, float* __restrict__ out) {
  int b = blockIdx.y, j = blockIdx.x;
  if (j >= selcnt[b]) return;
  int idx = selidx[b * KMAX + j];
  float val = selval[b * KMAX + j];
  int h = idx >> 13, t = idx & (TT - 1);
  int bx = t >> 7, tl = t & 127, nt = tl >> 5, m = tl & 31;
  int lane = threadIdx.x;  // 64
  const short* xt = xf + ((size_t)b * 64 + bx) * 16384 + nt * 4096 + m * 8;
  int off = (lane >> 3) * 512 + ((lane >> 2) & 1) * 256 + (lane & 3) * 2;
  __hip_bfloat162 hv = *(const __hip_bfloat162*)(xt + off);
  float2 xv = __bfloat1622float2(hv);
  int c0 = lane * 2;
  float2 wv = *(const float2*)(uw + (size_t)h * CC + c0);
  float p = xv.x * wv.x + xv.y * wv.y;
#pragma unroll
  for (int mm = 1; mm < 64; mm <<= 1) p += __shfl_xor(p, mm);
  float sig = p + ub[h];
  float g = sig * val;
  float2 dv = *(const float2*)(dwt + (size_t)h * CC + c0);
  atomicAdd(&out[((size_t)b * CC + c0) * TT + t], g * dv.x);
  atomicAdd(&out[((size_t)b * CC + c0 + 1) * TT + t], g * dv.y);
}

// ================= slow-path (R3, proven) kernels for small ws ======================
__global__ __launch_bounds__(256) void pass_a_slow(const float* __restrict__ x,
                                                   const float* __restrict__ sw,
                                                   const float* __restrict__ sb,
                                                   float* __restrict__ cellmax,
                                                   int* __restrict__ hist,
                                                   double* __restrict__ sumexp) {
  __shared__ short Ws[128 * 128];
  __shared__ short Xs[128 * 128];
  __shared__ float sbs[128];
  int tid = threadIdx.x;
  int b = blockIdx.z, by = blockIdx.y, bx = blockIdx.x;
  int h0 = by * 128, t0g = bx * 128;
  const float* xb = x + (size_t)b * CC * TT;
  {
    int cq = tid >> 5, tq = tid & 31;
    int t0 = tq * 4;
#pragma unroll
    for (int p = 0; p < 4; p++) {
      int c0 = p * 32 + cq * 4;
      float r0[4], r1[4], r2[4], r3[4];
      *(float4*)r0 = *(const float4*)(xb + (size_t)(c0 + 0) * TT + t0g + t0);
      *(float4*)r1 = *(const float4*)(xb + (size_t)(c0 + 1) * TT + t0g + t0);
      *(float4*)r2 = *(const float4*)(xb + (size_t)(c0 + 2) * TT + t0g + t0);
      *(float4*)r3 = *(const float4*)(xb + (size_t)(c0 + 3) * TT + t0g + t0);
#pragma unroll
      for (int j = 0; j < 4; j++) {
        int t = t0 + j;
        int addr = t * 128 + ((((c0 >> 3) ^ (t & 15)) << 3) | (c0 & 7));
        union { __hip_bfloat162 h; unsigned int u; } a0, a1;
        a0.h = __float22bfloat162_rn(make_float2(r0[j], r1[j]));
        a1.h = __float22bfloat162_rn(make_float2(r2[j], r3[j]));
        *(uint2*)&Xs[addr] = make_uint2(a0.u, a1.u);
      }
    }
  }
  {
    int hh = tid >> 1, c4 = (tid & 1) << 2;
#pragma unroll
    for (int k = 0; k < 16; k++) {
      int c0 = k * 8 + c4;
      float r[4];
      *(float4*)r = *(const float4*)(sw + (size_t)(h0 + hh) * CC + c0);
      int addr = hh * 128 + ((((c0 >> 3) ^ (hh & 15)) << 3) | (c0 & 7));
      union { __hip_bfloat162 h; unsigned int u; } a0, a1;
      a0.h = __float22bfloat162_rn(make_float2(r[0], r[1]));
      a1.h = __float22bfloat162_rn(make_float2(r[2], r[3]));
      *(uint2*)&Ws[addr] = make_uint2(a0.u, a1.u);
    }
  }
  if (tid < 128) sbs[tid] = sb[h0 + tid];
  __syncthreads();
  int w = tid >> 6, lane = tid & 63, m = lane & 31, u = lane >> 5;
  f32x16 acc0, acc1, acc2, acc3;
#pragma unroll
  for (int r = 0; r < 16; r++) { acc0[r] = 0.f; acc1[r] = 0.f; acc2[r] = 0.f; acc3[r] = 0.f; }
  const short* wrow = &Ws[(w * 32 + m) * 128];
  const short* xrow = &Xs[m * 128];
#pragma unroll
  for (int kc = 0; kc < 8; kc++) {
    int pc = ((((kc << 1) | u) ^ (m & 15)) << 3);
    short8 af = *(const short8*)(wrow + pc);
    short8 b0 = *(const short8*)(xrow + 0 * 32 * 128 + pc);
    short8 b1 = *(const short8*)(xrow + 1 * 32 * 128 + pc);
    short8 b2 = *(const short8*)(xrow + 2 * 32 * 128 + pc);
    short8 b3 = *(const short8*)(xrow + 3 * 32 * 128 + pc);
    acc0 = __builtin_amdgcn_mfma_f32_32x32x16_bf16(af, b0, acc0, 0, 0, 0);
    acc1 = __builtin_amdgcn_mfma_f32_32x32x16_bf16(af, b1, acc1, 0, 0, 0);
    acc2 = __builtin_amdgcn_mfma_f32_32x32x16_bf16(af, b2, acc2, 0, 0, 0);
    acc3 = __builtin_amdgcn_mfma_f32_32x32x16_bf16(af, b3, acc3, 0, 0, 0);
  }
  float tmax = -1e30f;
  float se = 0.f;
#define EPI(ACC)                                                              \
  {                                                                           \
    _Pragma("unroll") for (int g = 0; g < 4; g++) {                           \
      float bias4[4];                                                         \
      *(float4*)bias4 = *(float4*)&sbs[w * 32 + g * 8 + u * 4];               \
      _Pragma("unroll") for (int q = 0; q < 4; q++) {                         \
        float s = ACC[g * 4 + q] + bias4[q];                                  \
        tmax = fmaxf(tmax, s);                                                \
        se += __expf(s);                                                      \
        if (s >= HFLOOR) {                                                    \
          int bin = (int)((s - HFLOOR) * INVBW);                              \
          if (bin > NBIN - 1) bin = NBIN - 1;                                 \
          atomicAdd(&hist[b * NBIN + bin], 1);                                \
        }                                                                     \
      }                                                                       \
    }                                                                         \
  }
  EPI(acc0) EPI(acc1) EPI(acc2) EPI(acc3)
#undef EPI
  int cid = ((b * 4 + by) * 64 + bx) * 256 + tid;
  cellmax[cid] = tmax;
  double sed = (double)se;
#pragma unroll
  for (int mm = 1; mm < 64; mm <<= 1) sed += __shfl_xor(sed, mm);
  if ((tid & 63) == 0) atomicAdd(&sumexp[b], sed);
}

__global__ void pass_c1_slow(const float* __restrict__ cellmax, const float* __restrict__ tau,
                             int* __restrict__ hotcnt, int* __restrict__ hotlist) {
  int i = blockIdx.x * blockDim.x + threadIdx.x;
  float v = cellmax[i];
  int b = i >> 16;
  if (v >= tau[b] - DELTA_C1) {
    int pos = atomicAdd(hotcnt, 1);
    if (pos < HOTCAP) hotlist[pos] = i;
  }
}

__global__ void pass_c2_slow(const float* __restrict__ x, const float* __restrict__ sw,
                             const float* __restrict__ sb, const float* __restrict__ tau,
                             const int* __restrict__ hotcnt, const int* __restrict__ hotlist,
                             int* __restrict__ candcnt, double* __restrict__ candval,
                             int* __restrict__ candidx) {
  int j = blockIdx.x;
  int n = hotcnt[0];
  if (n > HOTCAP) n = HOTCAP;
  if (j >= n) return;
  int cid = hotlist[j];
  int b = cid >> 16, by = (cid >> 14) & 3, bx = (cid >> 8) & 63;
  int ta = cid & 255;
  int w = ta >> 6, lane = ta & 63, m = lane & 31, u = lane >> 5;
  int e = threadIdx.x;
  int nt = e >> 4, r = e & 15;
  int h = by * 128 + w * 32 + (r >> 2) * 8 + (r & 3) + 4 * u;
  int t = bx * 128 + nt * 32 + m;
  const float* xb = x + (size_t)b * CC * TT;
  double acc = 0.0;
#pragma unroll 8
  for (int c = 0; c < CC; c++)
    acc += (double)xb[(size_t)c * TT + t] * (double)sw[h * CC + c];
  acc += (double)sb[h];
  float tm = tau[b] - DELTA_C2;
  if (acc >= (double)tm) {
    int pos = atomicAdd(&candcnt[b], 1);
    if (pos < CANDCAP) {
      candval[b * CANDCAP + pos] = acc;
      candidx[b * CANDCAP + pos] = h * TT + t;
    }
  }
}

__global__ void pass_e2_slow(const float* __restrict__ x, const float* __restrict__ uw,
                             const float* __restrict__ ub, const float* __restrict__ dw,
                             const int* __restrict__ selidx, const float* __restrict__ selval,
                             const int* __restrict__ selcnt, float* __restrict__ out) {
  int b = blockIdx.y, j = blockIdx.x;
  if (j >= selcnt[b]) return;
  int idx = selidx[b * KMAX + j];
  float val = selval[b * KMAX + j];
  int h = idx >> 13, t = idx & (TT - 1);
  int c = threadIdx.x;
  const float* xb = x + (size_t)b * CC * TT;
  float p = xb[(size_t)c * TT + t] * uw[h * CC + c] +
            xb[(size_t)(c + 64) * TT + t] * uw[h * CC + c + 64];
#pragma unroll
  for (int m = 1; m < 64; m <<= 1) p += __shfl_xor(p, m);
  float sig = p + ub[h];
  float g = sig * val;
  atomicAdd(&out[((size_t)b * CC + c) * TT + t], g * dw[c * HH + h]);
  atomicAdd(&out[((size_t)b * CC + c + 64) * TT + t], g * dw[(c + 64) * HH + h]);
}

extern "C" void kernel_launch(void* const* d_in, const int* in_sizes, int n_in,
                              void* d_out, int out_size, void* d_ws, size_t ws_size,
                              hipStream_t stream) {
  const float* x = (const float*)d_in[0];
  const float* uw = (const float*)d_in[1];
  const float* ub = (const float*)d_in[2];
  const float* sw = (const float*)d_in[3];
  const float* sb = (const float*)d_in[4];
  const float* dw = (const float*)d_in[5];
  const float* db = (const float*)d_in[6];
  const int* kptr = (const int*)d_in[7];
  float* out = (float*)d_out;
  char* ws = (char*)d_ws;

  if (ws_size >= (size_t)N_NEED) {
    int* hist = (int*)(ws + N_HIST);
    double* sumexp = (double*)(ws + N_SUMEXP);
    int* candcnt = (int*)(ws + N_CANDCNT);
    int* tilecnt = (int*)(ws + N_TILECNT);
    float* tau = (float*)(ws + N_TAU);
    int* selcnt = (int*)(ws + N_SELCNT);
    float* cellmax = (float*)(ws + N_CELLMAX);
    int* tlist = (int*)(ws + N_TLIST);
    double* candval = (double*)(ws + N_CANDVAL);
    int* candidx = (int*)(ws + N_CANDIDX);
    int* selidx = (int*)(ws + N_SELIDX);
    float* selval = (float*)(ws + N_SELVAL);
    short* swb = (short*)(ws + N_SWB);
    short* xf = (short*)(ws + N_XF);
    float* dwt = (float*)(ws + N_DWT);

    (void)hipMemsetAsync(d_ws, 0, N_ZERO, stream);
    prep_w<<<32, 256, 0, stream>>>(sw, swb);
    prep_dwt<<<256, 256, 0, stream>>>(dw, dwt);
    prep_xt<<<dim3(64, 32), 256, 0, stream>>>(x, xf);
    pass_a_reg<<<dim3(256, 32), 256, 0, stream>>>(xf, swb, sb, cellmax, hist, sumexp);
    pass_b<<<32, 256, 0, stream>>>(hist, tau, kptr);
    pass_c1_fast<<<8192, 256, 0, stream>>>(cellmax, tau, tilecnt, tlist);
    pass_c2_fast<<<TILES, 256, 0, stream>>>(x, sw, sb, tau, tilecnt, tlist, candcnt,
                                            candval, candidx);
    pass_d<<<32, 256, 0, stream>>>(candcnt, candval, candidx, sumexp, kptr, selidx,
                                   selval, selcnt);
    pass_e1<<<BB * CC, 256, 0, stream>>>(db, out);
    pass_e2_fast<<<dim3(KMAX, BB), 64, 0, stream>>>(xf, uw, ub, dwt, selidx, selval,
                                                    selcnt, out);
  } else {
    int* hist = (int*)(ws + O_HIST);
    double* sumexp = (double*)(ws + O_SUMEXP);
    int* candcnt = (int*)(ws + O_CANDCNT);
    int* hotcnt = (int*)(ws + O_HOTCNT);
    float* tau = (float*)(ws + O_TAU);
    int* selcnt = (int*)(ws + O_SELCNT);
    float* cellmax = (float*)(ws + O_CELLMAX);
    int* hotlist = (int*)(ws + O_HOTLIST);
    double* candval = (double*)(ws + O_CANDVAL);
    int* candidx = (int*)(ws + O_CANDIDX);
    int* selidx = (int*)(ws + O_SELIDX);
    float* selval = (float*)(ws + O_SELVAL);

    (void)hipMemsetAsync(d_ws, 0, O_ZERO, stream);
    pass_a_slow<<<dim3(64, 4, 32), 256, 0, stream>>>(x, sw, sb, cellmax, hist, sumexp);
    pass_b<<<32, 256, 0, stream>>>(hist, tau, kptr);
    pass_c1_slow<<<8192, 256, 0, stream>>>(cellmax, tau, hotcnt, hotlist);
    pass_c2_slow<<<HOTCAP, 64, 0, stream>>>(x, sw, sb, tau, hotcnt, hotlist, candcnt,
                                            candval, candidx);
    pass_d<<<32, 256, 0, stream>>>(candcnt, candval, candidx, sumexp, kptr, selidx,
                                   selval, selcnt);
    pass_e1<<<BB * CC, 256, 0, stream>>>(db, out);
    pass_e2_slow<<<dim3(KMAX, BB), 64, 0, stream>>>(x, uw, ub, dw, selidx, selval,
                                                    selcnt, out);
  }
}